// Round 8
// baseline (353.779 us; speedup 1.0000x reference)
//
#include <hip/hip_runtime.h>
#include <hip/hip_bf16.h>
#include <math.h>

typedef __attribute__((ext_vector_type(8))) short bf16x8;
typedef __attribute__((ext_vector_type(4))) float f32x4;
typedef unsigned short u16;

__device__ __forceinline__ float gelu_f(float x) {
    float x3 = x * x * x;
    return 0.5f * x * (1.0f + tanhf(0.7978845608028654f * (x + 0.044715f * x3)));
}
__device__ __forceinline__ void bf_split(float v, u16& hi, u16& lo) {
    __hip_bfloat16 h = __float2bfloat16(v);
    hi = *(u16*)&h;
    float r = v - __bfloat162float(h);
    __hip_bfloat16 l = __float2bfloat16(r);
    lo = *(u16*)&l;
}

// ---------------- fused tsym + x0 + LN (+ tsym store), one row per block ----------------
__global__ __launch_bounds__(256) void x0row_k(const float* __restrict__ topo,
                                               const float* __restrict__ weight,
                                               const float* __restrict__ w_topo,
                                               const float* __restrict__ b_topo,
                                               const float* __restrict__ w_w,
                                               const float* __restrict__ b_w,
                                               const float* __restrict__ n_emb,
                                               float* __restrict__ tsym,
                                               float* __restrict__ x,
                                               u16* __restrict__ hhi, u16* __restrict__ hlo) {
    int bn = blockIdx.x;                 // 0..511
    int b = bn >> 7, n = bn & 127;
    int tid = threadIdx.x;
    __shared__ float tsr[128];
    __shared__ float red[256];
    if (tid < 128) {
        float v = topo[bn * 128 + tid] + topo[(b << 14) + (tid << 7) + n];
        tsr[tid] = v;
        tsym[bn * 128 + tid] = v;
    }
    __syncthreads();
    int c0 = tid, c1 = tid + 256;
    float acc0 = 0.f, acc1 = 0.f;
#pragma unroll 4
    for (int m = 0; m < 128; ++m) {
        float t = tsr[m];
        acc0 += t * w_topo[m * 512 + c0];
        acc1 += t * w_topo[m * 512 + c1];
    }
    float wgt = weight[bn];
    float v0 = acc0 + b_topo[c0] + wgt * w_w[c0] + b_w[c0] + n_emb[n * 512 + c0];
    float v1 = acc1 + b_topo[c1] + wgt * w_w[c1] + b_w[c1] + n_emb[n * 512 + c1];
    x[bn * 512 + c0] = v0;
    x[bn * 512 + c1] = v1;
    red[tid] = v0 + v1;
    __syncthreads();
    for (int off = 128; off > 0; off >>= 1) { if (tid < off) red[tid] += red[tid + off]; __syncthreads(); }
    float mean = red[0] * (1.0f / 512.0f);
    __syncthreads();
    float d0 = v0 - mean, d1 = v1 - mean;
    red[tid] = d0 * d0 + d1 * d1;
    __syncthreads();
    for (int off = 128; off > 0; off >>= 1) { if (tid < off) red[tid] += red[tid + off]; __syncthreads(); }
    float rs = rsqrtf(red[0] * (1.0f / 512.0f) + 1e-6f);
    u16 h, l;
    bf_split(d0 * rs, h, l); hhi[bn * 512 + c0] = h; hlo[bn * 512 + c0] = l;
    bf_split(d1 * rs, h, l); hhi[bn * 512 + c1] = h; hlo[bn * 512 + c1] = l;
}

// ---------------- weight transpose + bf16-split prep ----------------
__global__ __launch_bounds__(256) void prep_k(
    const float* __restrict__ wq, const float* __restrict__ wk, const float* __restrict__ wv,
    const float* __restrict__ wo, const float* __restrict__ w1, const float* __restrict__ w2,
    const float* __restrict__ ew1,
    u16* __restrict__ qkvt_h, u16* __restrict__ qkvt_l,
    u16* __restrict__ wot_h, u16* __restrict__ wot_l,
    u16* __restrict__ w1t_h, u16* __restrict__ w1t_l,
    u16* __restrict__ w2t_h, u16* __restrict__ w2t_l,
    u16* __restrict__ eabt_h, u16* __restrict__ eabt_l,
    u16* __restrict__ ect_h, u16* __restrict__ ect_l) {
    __shared__ u16 Hs[64][68];
    __shared__ u16 Ls[64][68];
    int bid = blockIdx.x;
    int region, tr, KK;
    u16 *dh, *dl;
    if (bid < 768)       { region = 0; tr = bid;        KK = 512;  dh = qkvt_h; dl = qkvt_l; }
    else if (bid < 1024) { region = 1; tr = bid - 768;  KK = 512;  dh = wot_h;  dl = wot_l; }
    else if (bid < 2048) { region = 2; tr = bid - 1024; KK = 512;  dh = w1t_h;  dl = w1t_l; }
    else if (bid < 3072) { region = 3; tr = bid - 2048; KK = 2048; dh = w2t_h;  dl = w2t_l; }
    else if (bid < 3088) { region = 4; tr = bid - 3072; KK = 512;  dh = eabt_h; dl = eabt_l; }
    else                 { region = 5; tr = bid - 3088; KK = 512;  dh = ect_h;  dl = ect_l; }
    int ktiles = KK >> 6;
    int tn = tr / ktiles, tk = tr % ktiles;
    int k0 = tk * 64, n0g = tn * 64;
    int tid = threadIdx.x;
#pragma unroll
    for (int p = 0; p < 4; ++p) {
        int kk = p * 16 + (tid >> 4);
        int nn = (tid & 15) * 4;
        int kg = k0 + kk, ng = n0g + nn;
        const float* src;
        if (region == 0) {
            int d = ng / 1536; int nr = ng - d * 1536; int sel = nr >> 9; int nc = nr & 511;
            const float* w = sel == 0 ? wq : (sel == 1 ? wk : wv);
            src = w + ((size_t)(d * 512 + kg)) * 512 + nc;
        } else if (region == 1) {
            int d = ng >> 9; int nc = ng & 511;
            src = wo + ((size_t)(d * 512 + kg)) * 512 + nc;
        } else if (region == 2) {
            int d = ng >> 11; int nc = ng & 2047;
            src = w1 + ((size_t)(d * 512 + kg)) * 2048 + nc;
        } else if (region == 3) {
            int d = ng >> 9; int nc = ng & 511;
            src = w2 + ((size_t)(d * 2048 + kg)) * 512 + nc;
        } else if (region == 4) {
            src = (ng < 64) ? (ew1 + (size_t)kg * 64 + ng) : (ew1 + (size_t)(512 + kg) * 64 + (ng - 64));
        } else {
            src = ew1 + (size_t)(1024 + kg) * 64 + ng;
        }
        float4 v = *(const float4*)src;
        u16 h0, l0, h1, l1, h2, l2, h3, l3;
        bf_split(v.x, h0, l0); bf_split(v.y, h1, l1);
        bf_split(v.z, h2, l2); bf_split(v.w, h3, l3);
        *(ushort4*)&Hs[kk][nn] = make_ushort4(h0, h1, h2, h3);
        *(ushort4*)&Ls[kk][nn] = make_ushort4(l0, l1, l2, l3);
    }
    __syncthreads();
#pragma unroll
    for (int p = 0; p < 2; ++p) {
        int chunk = p * 256 + tid;
        int nl = chunk >> 3;
        int k8 = (chunk & 7) * 8;
        ushort4 ha, hb, la, lb;
        ha.x = Hs[k8 + 0][nl]; ha.y = Hs[k8 + 1][nl]; ha.z = Hs[k8 + 2][nl]; ha.w = Hs[k8 + 3][nl];
        hb.x = Hs[k8 + 4][nl]; hb.y = Hs[k8 + 5][nl]; hb.z = Hs[k8 + 6][nl]; hb.w = Hs[k8 + 7][nl];
        la.x = Ls[k8 + 0][nl]; la.y = Ls[k8 + 1][nl]; la.z = Ls[k8 + 2][nl]; la.w = Ls[k8 + 3][nl];
        lb.x = Ls[k8 + 4][nl]; lb.y = Ls[k8 + 5][nl]; lb.z = Ls[k8 + 6][nl]; lb.w = Ls[k8 + 7][nl];
        size_t dst = (size_t)(n0g + nl) * KK + k0 + k8;
        *(ushort4*)(dh + dst) = ha; *(ushort4*)(dh + dst + 4) = hb;
        *(ushort4*)(dl + dst) = la; *(ushort4*)(dl + dst + 4) = lb;
    }
}

// ---------------- LDS-staged double-buffered split-bf16 MFMA GEMM ----------------
template <int KC, bool PARTIAL, bool GELU, bool RES, bool OUTF, bool OUTS, bool EBIAS>
__global__ __launch_bounds__(256) void gemm2(
    const u16* __restrict__ Ahi, const u16* __restrict__ Alo,
    const u16* __restrict__ Whi, const u16* __restrict__ Wlo,
    const float* __restrict__ bias, const float* __restrict__ Rres,
    float* __restrict__ C, u16* __restrict__ Chi, u16* __restrict__ Clo,
    float* __restrict__ part, int lda, int N) {
    __shared__ u16 sbuf[2][2][64][64];  // [buf][A/B][row][hi32|lo32]
    const int tid = threadIdx.x;
    const int l = tid & 63;
    const int w = tid >> 6;
    const int bn0 = blockIdx.x * 64;
    const int bm0 = blockIdx.y * 64;
    const int z = blockIdx.z;

    const u16* gp[4];
#pragma unroll
    for (int i = 0; i < 4; ++i) {
        int o = (i * 4 + w) * 1024 + l * 16;
        int mat = o >> 13;
        int r = (o >> 7) & 63;
        int slot = (o >> 4) & 7;
        int lslot = slot ^ (r & 7);
        int sel = lslot >> 2;
        int kel = (lslot & 3) * 8;
        const u16* basep;
        if (mat == 0) basep = (sel ? Alo : Ahi) + (size_t)(bm0 + r) * lda;
        else          basep = (sel ? Wlo : Whi) + (size_t)(bn0 + r) * lda;
        gp[i] = basep + kel + z * KC;
    }

    f32x4 acc[2][2] = {};
    constexpr int S = KC / 32;

    auto stage = [&](int buf, int ko) {
#pragma unroll
        for (int i = 0; i < 4; ++i) {
            __builtin_amdgcn_global_load_lds(
                (const __attribute__((address_space(1))) void*)(gp[i] + ko),
                (__attribute__((address_space(3))) void*)((char*)&sbuf[buf][0][0][0] + (i * 4 + w) * 1024),
                16, 0, 0);
        }
    };
    auto compute = [&](int buf) {
        bf16x8 a[2][2], b[2][2];
        int rA0 = (w & 1) * 32 + (l & 15);
        int rB0 = (w >> 1) * 32 + (l & 15);
        int lsl = l >> 4;
#pragma unroll
        for (int f = 0; f < 2; ++f) {
            int rA = rA0 + f * 16;
            int rB = rB0 + f * 16;
#pragma unroll
            for (int sel = 0; sel < 2; ++sel) {
                int psA = (lsl + sel * 4) ^ (rA & 7);
                int psB = (lsl + sel * 4) ^ (rB & 7);
                a[f][sel] = *(const bf16x8*)&sbuf[buf][0][rA][psA * 8];
                b[f][sel] = *(const bf16x8*)&sbuf[buf][1][rB][psB * 8];
            }
        }
#pragma unroll
        for (int fm = 0; fm < 2; ++fm)
#pragma unroll
            for (int fn = 0; fn < 2; ++fn) {
                acc[fm][fn] = __builtin_amdgcn_mfma_f32_16x16x32_bf16(a[fm][0], b[fn][0], acc[fm][fn], 0, 0, 0);
                acc[fm][fn] = __builtin_amdgcn_mfma_f32_16x16x32_bf16(a[fm][0], b[fn][1], acc[fm][fn], 0, 0, 0);
                acc[fm][fn] = __builtin_amdgcn_mfma_f32_16x16x32_bf16(a[fm][1], b[fn][0], acc[fm][fn], 0, 0, 0);
            }
    };

    stage(0, 0);
    __syncthreads();
#pragma unroll
    for (int s = 0; s < S; ++s) {
        if (s + 1 < S) stage((s + 1) & 1, (s + 1) * 32);
        compute(s & 1);
        __syncthreads();
    }

    int rb = bm0 + (w & 1) * 32 + (l >> 4) * 4;
    int cb = bn0 + (w >> 1) * 32 + (l & 15);
#pragma unroll
    for (int fm = 0; fm < 2; ++fm)
#pragma unroll
        for (int fn = 0; fn < 2; ++fn) {
            int col = cb + fn * 16;
            float bv;
            if (PARTIAL) bv = 0.f;
            else if (EBIAS) bv = col < 64 ? bias[col] : 0.f;
            else bv = bias[col];
#pragma unroll
            for (int r = 0; r < 4; ++r) {
                int row = rb + fm * 16 + r;
                float v = acc[fm][fn][r] + bv;
                if (PARTIAL) {
                    part[(size_t)z * 512 * N + (size_t)row * N + col] = v;
                } else {
                    if (GELU) v = gelu_f(v);
                    if (RES) v += Rres[(size_t)row * N + col];
                    if (OUTF) C[(size_t)row * N + col] = v;
                    if (OUTS) {
                        u16 h, lo2; bf_split(v, h, lo2);
                        Chi[(size_t)row * N + col] = h; Clo[(size_t)row * N + col] = lo2;
                    }
                }
            }
        }
}

// ---------------- split-K reduce + bias + residual -> x, then LN (or raw split) ----------------
template <int NZ, bool DOLN, bool DOSPLITX>
__global__ __launch_bounds__(256) void redln_k(const float* __restrict__ part,
                                               const float* __restrict__ bias,
                                               float* __restrict__ x,
                                               u16* __restrict__ hhi, u16* __restrict__ hlo) {
    int row = blockIdx.x;
    int tid = threadIdx.x;
    int c0 = tid, c1 = tid + 256;
    float v0 = bias[c0], v1 = bias[c1];
#pragma unroll
    for (int z = 0; z < NZ; ++z) {
        v0 += part[(size_t)z * 262144 + row * 512 + c0];
        v1 += part[(size_t)z * 262144 + row * 512 + c1];
    }
    v0 += x[row * 512 + c0];
    v1 += x[row * 512 + c1];
    x[row * 512 + c0] = v0;
    x[row * 512 + c1] = v1;
    u16 h, l;
    if (DOSPLITX) {
        bf_split(v0, h, l); hhi[row * 512 + c0] = h; hlo[row * 512 + c0] = l;
        bf_split(v1, h, l); hhi[row * 512 + c1] = h; hlo[row * 512 + c1] = l;
    }
    if (DOLN) {
        __shared__ float red[256];
        red[tid] = v0 + v1;
        __syncthreads();
        for (int off = 128; off > 0; off >>= 1) { if (tid < off) red[tid] += red[tid + off]; __syncthreads(); }
        float mean = red[0] * (1.0f / 512.0f);
        __syncthreads();
        float d0 = v0 - mean, d1 = v1 - mean;
        red[tid] = d0 * d0 + d1 * d1;
        __syncthreads();
        for (int off = 128; off > 0; off >>= 1) { if (tid < off) red[tid] += red[tid + off]; __syncthreads(); }
        float rs = rsqrtf(red[0] * (1.0f / 512.0f) + 1e-6f);
        bf_split(d0 * rs, h, l); hhi[row * 512 + c0] = h; hlo[row * 512 + c0] = l;
        bf_split(d1 * rs, h, l); hhi[row * 512 + c1] = h; hlo[row * 512 + c1] = l;
    }
}

// ---------------- fused masked attention; reads QKV split-K partials + biases directly ----------------
__global__ __launch_bounds__(256) void attn_k(const float* __restrict__ pw,
                                              const float* __restrict__ bq,
                                              const float* __restrict__ bk,
                                              const float* __restrict__ bv,
                                              const float* __restrict__ tsym,
                                              u16* __restrict__ agghi, u16* __restrict__ agglo) {
    int tt = blockIdx.x, hh = blockIdx.y, b = blockIdx.z;
    __shared__ __align__(16) float Ks[128 * 68];
    __shared__ __align__(16) float Vt[64 * 132];
    __shared__ __align__(16) float Ss[16 * 132];
    __shared__ __align__(16) float Qs[16][68];
    int tid = threadIdx.x;
    {
        int j = tid >> 1, c0 = (tid & 1) * 32;
        const float* kr0 = pw + (size_t)(b * 128 + j) * 1536 + 512 + hh * 64 + c0;
        const float* kr1 = kr0 + 786432;
        const float* bkp = bk + hh * 64 + c0;
        const float* bvp = bv + hh * 64 + c0;
#pragma unroll
        for (int c = 0; c < 32; c += 4) {
            float4 k0v = *(const float4*)(kr0 + c);
            float4 k1v = *(const float4*)(kr1 + c);
            float4 v0v = *(const float4*)(kr0 + 512 + c);
            float4 v1v = *(const float4*)(kr1 + 512 + c);
            float4 bkv = *(const float4*)(bkp + c);
            float4 bvv = *(const float4*)(bvp + c);
            Ks[j * 68 + c0 + c + 0] = k0v.x + k1v.x + bkv.x;
            Ks[j * 68 + c0 + c + 1] = k0v.y + k1v.y + bkv.y;
            Ks[j * 68 + c0 + c + 2] = k0v.z + k1v.z + bkv.z;
            Ks[j * 68 + c0 + c + 3] = k0v.w + k1v.w + bkv.w;
            Vt[(c0 + c + 0) * 132 + j] = v0v.x + v1v.x + bvv.x;
            Vt[(c0 + c + 1) * 132 + j] = v0v.y + v1v.y + bvv.y;
            Vt[(c0 + c + 2) * 132 + j] = v0v.z + v1v.z + bvv.z;
            Vt[(c0 + c + 3) * 132 + j] = v0v.w + v1v.w + bvv.w;
        }
    }
    {
        int rid = tid >> 4, c4 = (tid & 15) * 4;
        int grow = b * 128 + tt * 16 + rid;
        const float* q0 = pw + (size_t)grow * 1536 + hh * 64 + c4;
        float4 a = *(const float4*)q0;
        float4 a1 = *(const float4*)(q0 + 786432);
        float4 bb = *(const float4*)(bq + hh * 64 + c4);
        Qs[rid][c4 + 0] = a.x + a1.x + bb.x;
        Qs[rid][c4 + 1] = a.y + a1.y + bb.y;
        Qs[rid][c4 + 2] = a.z + a1.z + bb.z;
        Qs[rid][c4 + 3] = a.w + a1.w + bb.w;
    }
    __syncthreads();
    {
        int j = tid & 127, th = tid >> 7;
        float acc[8] = {0.f, 0.f, 0.f, 0.f, 0.f, 0.f, 0.f, 0.f};
        for (int d0 = 0; d0 < 64; d0 += 4) {
            float4 kv = *(const float4*)&Ks[j * 68 + d0];
#pragma unroll
            for (int r = 0; r < 8; ++r) {
                float4 qv = *(const float4*)&Qs[th * 8 + r][d0];
                acc[r] += qv.x * kv.x + qv.y * kv.y + qv.z * kv.z + qv.w * kv.w;
            }
        }
        const float* tsr = tsym + ((size_t)b << 14) + (size_t)(tt * 16 + th * 8) * 128 + j;
#pragma unroll
        for (int r = 0; r < 8; ++r) {
            int t = th * 8 + r;
            float sv = (tsr[r * 128] > 0.f) ? acc[r] * 0.125f : -INFINITY;
            Ss[t * 132 + j] = sv;
        }
    }
    __syncthreads();
    {
        int row = tid >> 4, l16 = tid & 15;
        float v[8]; float m = -INFINITY;
#pragma unroll
        for (int c = 0; c < 8; ++c) { v[c] = Ss[row * 132 + l16 + c * 16]; m = fmaxf(m, v[c]); }
#pragma unroll
        for (int off = 8; off; off >>= 1) m = fmaxf(m, __shfl_xor(m, off));
        float ssum = 0.f;
#pragma unroll
        for (int c = 0; c < 8; ++c) {
            float e = (v[c] == -INFINITY) ? 0.f : __expf(v[c] - m);
            v[c] = e; ssum += e;
        }
#pragma unroll
        for (int off = 8; off; off >>= 1) ssum += __shfl_xor(ssum, off);
        float inv = 1.0f / (ssum + 1e-12f);
#pragma unroll
        for (int c = 0; c < 8; ++c) Ss[row * 132 + l16 + c * 16] = v[c] * inv;
    }
    __syncthreads();
    {
        int d = tid & 63, tq = tid >> 6;
        float a0 = 0.f, a1 = 0.f, a2 = 0.f, a3 = 0.f;
        for (int j0 = 0; j0 < 128; j0 += 4) {
            float4 vv = *(const float4*)&Vt[d * 132 + j0];
            float4 s0 = *(const float4*)&Ss[(tq * 4 + 0) * 132 + j0];
            float4 s1 = *(const float4*)&Ss[(tq * 4 + 1) * 132 + j0];
            float4 s2 = *(const float4*)&Ss[(tq * 4 + 2) * 132 + j0];
            float4 s3 = *(const float4*)&Ss[(tq * 4 + 3) * 132 + j0];
            a0 += s0.x * vv.x + s0.y * vv.y + s0.z * vv.z + s0.w * vv.w;
            a1 += s1.x * vv.x + s1.y * vv.y + s1.z * vv.z + s1.w * vv.w;
            a2 += s2.x * vv.x + s2.y * vv.y + s2.z * vv.z + s2.w * vv.w;
            a3 += s3.x * vv.x + s3.y * vv.y + s3.z * vv.z + s3.w * vv.w;
        }
        float accv[4] = {a0, a1, a2, a3};
        int growbase = b * 128 + tt * 16;
#pragma unroll
        for (int i = 0; i < 4; ++i) {
            int t = tq * 4 + i;
            u16 h, l; bf_split(accv[i], h, l);
            size_t o = (size_t)(growbase + t) * 512 + hh * 64 + d;
            agghi[o] = h; agglo[o] = l;
        }
    }
}

// ---------------- aebe reduce (inline concat bias) ----------------
__global__ __launch_bounds__(256) void redae_k(const float* __restrict__ part,
                                               const float* __restrict__ eb1,
                                               float* __restrict__ aebe) {
    int idx = blockIdx.x * 256 + threadIdx.x;   // 512*128
    int col = idx & 127;
    float v = col < 64 ? eb1[col] : 0.0f;
#pragma unroll
    for (int z = 0; z < 4; ++z) v += part[(size_t)z * 65536 + idx];
    aebe[idx] = v;
}

// ---------------- fused per-edge MLP: 16 edges/block, waves = (K-half x N-half) ----------------
__global__ __launch_bounds__(256) void edgemlp_k(const int* __restrict__ ei, int E,
                                                 const float* __restrict__ x,
                                                 const float* __restrict__ aebe,
                                                 const u16* __restrict__ ect_h, const u16* __restrict__ ect_l,
                                                 const float* __restrict__ ew2, const float* __restrict__ eb2,
                                                 const float* __restrict__ ew3, const float* __restrict__ eb3,
                                                 float* __restrict__ P) {
    __shared__ float partb[16][68];   // kz=1 partials (16 edges x 64 cols)
    __shared__ float G1[16][66];
    __shared__ float G2[16][66];
    __shared__ int s_src[16], s_dst[16];
    int tid = threadIdx.x;
    int e0 = blockIdx.x * 16;
    if (tid < 16) {
        int e = e0 + tid;
        s_src[tid] = e < E ? ei[e] : 0;
        s_dst[tid] = e < E ? ei[E + e] : 0;
    }
    __syncthreads();
    int lane = tid & 63, w = tid >> 6;
    int kz = w & 1;                      // K half: [0,256) or [256,512)
    int nf = (w >> 1) * 32;              // N half: cols [nf, nf+32)
    int l15 = lane & 15;
    int kf = (lane >> 4) * 8;
    int kbase = kz * 256 + kf;
    const float* xi = x + (size_t)s_src[l15] * 512 + kbase;
    const float* xj = x + (size_t)s_dst[l15] * 512 + kbase;
    const u16* pB1h = ect_h + (size_t)(nf + l15) * 512 + kbase;
    const u16* pB1l = ect_l + (size_t)(nf + l15) * 512 + kbase;
    const u16* pB2h = ect_h + (size_t)(nf + 16 + l15) * 512 + kbase;
    const u16* pB2l = ect_l + (size_t)(nf + 16 + l15) * 512 + kbase;
    f32x4 acc0 = {0.f, 0.f, 0.f, 0.f}, acc1 = {0.f, 0.f, 0.f, 0.f};
#pragma unroll
    for (int k0 = 0; k0 < 256; k0 += 32) {
        float4 xa = *(const float4*)(xi + k0);
        float4 xb = *(const float4*)(xi + k0 + 4);
        float4 ya = *(const float4*)(xj + k0);
        float4 yb = *(const float4*)(xj + k0 + 4);
        float p[8] = {xa.x * ya.x, xa.y * ya.y, xa.z * ya.z, xa.w * ya.w,
                      xb.x * yb.x, xb.y * yb.y, xb.z * yb.z, xb.w * yb.w};
        bf16x8 ah, al;
#pragma unroll
        for (int q2 = 0; q2 < 8; ++q2) {
            u16 h, l; bf_split(p[q2], h, l);
            ah[q2] = (short)h; al[q2] = (short)l;
        }
        bf16x8 b1h = *(const bf16x8*)(pB1h + k0);
        bf16x8 b1l = *(const bf16x8*)(pB1l + k0);
        bf16x8 b2h = *(const bf16x8*)(pB2h + k0);
        bf16x8 b2l = *(const bf16x8*)(pB2l + k0);
        acc0 = __builtin_amdgcn_mfma_f32_16x16x32_bf16(ah, b1h, acc0, 0, 0, 0);
        acc1 = __builtin_amdgcn_mfma_f32_16x16x32_bf16(ah, b2h, acc1, 0, 0, 0);
        acc0 = __builtin_amdgcn_mfma_f32_16x16x32_bf16(ah, b1l, acc0, 0, 0, 0);
        acc1 = __builtin_amdgcn_mfma_f32_16x16x32_bf16(ah, b2l, acc1, 0, 0, 0);
        acc0 = __builtin_amdgcn_mfma_f32_16x16x32_bf16(al, b1h, acc0, 0, 0, 0);
        acc1 = __builtin_amdgcn_mfma_f32_16x16x32_bf16(al, b2h, acc1, 0, 0, 0);
    }
    int rb = (lane >> 4) * 4;            // output rows rb..rb+3 (edges)
    if (kz == 1) {
#pragma unroll
        for (int f = 0; f < 2; ++f) {
            f32x4 a = f ? acc1 : acc0;
            int col = nf + f * 16 + l15;
#pragma unroll
            for (int r = 0; r < 4; ++r) partb[rb + r][col] = a[r];
        }
    }
    __syncthreads();
    if (kz == 0) {
#pragma unroll
        for (int f = 0; f < 2; ++f) {
            f32x4 a = f ? acc1 : acc0;
            int col = nf + f * 16 + l15;
#pragma unroll
            for (int r = 0; r < 4; ++r) {
                int e = rb + r;
                float c = a[r] + partb[e][col]
                        + aebe[(size_t)s_src[e] * 128 + col] + aebe[(size_t)s_dst[e] * 128 + 64 + col];
                G1[e][col] = gelu_f(c);
            }
        }
    }
    __syncthreads();
    {
        int col = tid & 63, eq = tid >> 6;   // eq 0..3, 4 edges each
        float acc[4];
#pragma unroll
        for (int i = 0; i < 4; ++i) acc[i] = eb2[col];
        for (int m = 0; m < 64; ++m) {
            float wv = ew2[m * 64 + col];
#pragma unroll
            for (int i = 0; i < 4; ++i) acc[i] += G1[eq * 4 + i][m] * wv;
        }
#pragma unroll
        for (int i = 0; i < 4; ++i) G2[eq * 4 + i][col] = gelu_f(acc[i]);
    }
    __syncthreads();
    {
        int el2 = tid >> 4, c4 = (tid & 15) * 4;   // 16 lanes per edge, 4 cols each
        float p = G2[el2][c4] * ew3[c4] + G2[el2][c4 + 1] * ew3[c4 + 1]
                + G2[el2][c4 + 2] * ew3[c4 + 2] + G2[el2][c4 + 3] * ew3[c4 + 3];
        p += __shfl_xor(p, 1); p += __shfl_xor(p, 2); p += __shfl_xor(p, 4); p += __shfl_xor(p, 8);
        if ((tid & 15) == 0 && e0 + el2 < E) {
            float logit = p + eb3[0];
            int s = s_src[el2], d2 = s_dst[el2];
            int bB = s >> 7, i2 = s & 127, j2 = d2 & 127;
            P[(bB << 14) + (i2 << 7) + j2] = 1.0f / (1.0f + expf(-logit));
        }
    }
}

// ---------------- final symmetrize + mask ----------------
__global__ __launch_bounds__(256) void final_k(const float* __restrict__ tsym,
                                               const float* __restrict__ P,
                                               float* __restrict__ out) {
    int idx = blockIdx.x * 256 + threadIdx.x;
    int b = idx >> 14, i = (idx >> 7) & 127, j = idx & 127;
    float o = 0.0f;
    if (i != j && tsym[idx] > 0.0f)
        o = 0.5f * (P[idx] + P[(b << 14) + (j << 7) + i]);
    out[idx] = o;
}

extern "C" void kernel_launch(void* const* d_in, const int* in_sizes, int n_in,
                              void* d_out, int out_size, void* d_ws, size_t ws_size,
                              hipStream_t stream) {
    const float* topo   = (const float*)d_in[0];
    const float* weight = (const float*)d_in[1];
    const int*   ei     = (const int*)d_in[2];
    const float* w_topo = (const float*)d_in[3];
    const float* b_topo = (const float*)d_in[4];
    const float* w_w    = (const float*)d_in[5];
    const float* b_w    = (const float*)d_in[6];
    const float* n_emb  = (const float*)d_in[7];
    const float* wq = (const float*)d_in[8];  const float* bq = (const float*)d_in[9];
    const float* wk = (const float*)d_in[10]; const float* bk = (const float*)d_in[11];
    const float* wv = (const float*)d_in[12]; const float* bv = (const float*)d_in[13];
    const float* wo = (const float*)d_in[14]; const float* bo = (const float*)d_in[15];
    const float* w1 = (const float*)d_in[16]; const float* b1 = (const float*)d_in[17];
    const float* w2 = (const float*)d_in[18]; const float* b2 = (const float*)d_in[19];
    const float* ew1 = (const float*)d_in[20]; const float* eb1 = (const float*)d_in[21];
    const float* ew2 = (const float*)d_in[22]; const float* eb2 = (const float*)d_in[23];
    const float* ew3 = (const float*)d_in[24]; const float* eb3 = (const float*)d_in[25];
    const int E = in_sizes[2] / 2;

    char* base = (char*)d_ws;
    size_t off = 0;
    auto alloc = [&](size_t bytes) { char* p = base + off; off += (bytes + 255) & ~(size_t)255; return p; };
    u16* qkvt_h = (u16*)alloc(3145728 * 2); u16* qkvt_l = (u16*)alloc(3145728 * 2);
    u16* wot_h  = (u16*)alloc(1048576 * 2); u16* wot_l  = (u16*)alloc(1048576 * 2);
    u16* w1t_h  = (u16*)alloc(4194304 * 2); u16* w1t_l  = (u16*)alloc(4194304 * 2);
    u16* w2t_h  = (u16*)alloc(4194304 * 2); u16* w2t_l  = (u16*)alloc(4194304 * 2);
    u16* eabt_h = (u16*)alloc(65536 * 2);   u16* eabt_l = (u16*)alloc(65536 * 2);
    u16* ect_h  = (u16*)alloc(32768 * 2);   u16* ect_l  = (u16*)alloc(32768 * 2);
    u16* h_hi   = (u16*)alloc(262144 * 2);  u16* h_lo   = (u16*)alloc(262144 * 2);
    u16* agg_hi = (u16*)alloc(262144 * 2);  u16* agg_lo = (u16*)alloc(262144 * 2);
    u16* mid_hi = (u16*)alloc(1048576 * 2); u16* mid_lo = (u16*)alloc(1048576 * 2);
    u16* x_hi   = (u16*)alloc(262144 * 2);  u16* x_lo   = (u16*)alloc(262144 * 2);
    float* tsym  = (float*)alloc(65536 * 4);
    float* x     = (float*)alloc(262144 * 4);
    float* aebe  = (float*)alloc(65536 * 4);
    float* P     = (float*)alloc(65536 * 4);
    float* pw    = (float*)alloc(1572864 * 4);   // split-K partials (max: qkv 2x512x1536)

    prep_k<<<3096, 256, 0, stream>>>(wq, wk, wv, wo, w1, w2, ew1,
                                     qkvt_h, qkvt_l, wot_h, wot_l, w1t_h, w1t_l,
                                     w2t_h, w2t_l, eabt_h, eabt_l, ect_h, ect_l);
    x0row_k<<<512, 256, 0, stream>>>(topo, weight, w_topo, b_topo, w_w, b_w, n_emb,
                                     tsym, x, h_hi, h_lo);

    for (int d = 0; d < 4; ++d) {
        // QKV: split-K x2 -> partials; bias+reduce fused into attn
        gemm2<256, true, false, false, false, false, false><<<dim3(24, 8, 2), 256, 0, stream>>>(
            h_hi, h_lo, qkvt_h + (size_t)d * 1536 * 512, qkvt_l + (size_t)d * 1536 * 512,
            nullptr, nullptr, nullptr, nullptr, nullptr, pw, 512, 1536);
        attn_k<<<dim3(8, 8, 4), 256, 0, stream>>>(pw, bq + d * 512, bk + d * 512, bv + d * 512,
                                                  tsym, agg_hi, agg_lo);
        // WO: split-K x4 -> partials -> fused reduce+res+LN
        gemm2<128, true, false, false, false, false, false><<<dim3(8, 8, 4), 256, 0, stream>>>(
            agg_hi, agg_lo, wot_h + (size_t)d * 512 * 512, wot_l + (size_t)d * 512 * 512,
            nullptr, nullptr, nullptr, nullptr, nullptr, pw, 512, 512);
        redln_k<4, true, false><<<512, 256, 0, stream>>>(pw, bo + d * 512, x, h_hi, h_lo);
        // MLP1: full-K, gelu + split out
        gemm2<512, false, true, false, false, true, false><<<dim3(32, 8, 1), 256, 0, stream>>>(
            h_hi, h_lo, w1t_h + (size_t)d * 2048 * 512, w1t_l + (size_t)d * 2048 * 512,
            b1 + d * 2048, nullptr, nullptr, mid_hi, mid_lo, nullptr, 512, 2048);
        // MLP2: split-K x4 -> partials -> fused reduce+res (+LN | +split)
        gemm2<512, true, false, false, false, false, false><<<dim3(8, 8, 4), 256, 0, stream>>>(
            mid_hi, mid_lo, w2t_h + (size_t)d * 512 * 2048, w2t_l + (size_t)d * 512 * 2048,
            nullptr, nullptr, nullptr, nullptr, nullptr, pw, 2048, 512);
        if (d < 3) {
            redln_k<4, true, false><<<512, 256, 0, stream>>>(pw, b2 + d * 512, x, h_hi, h_lo);
        } else {
            redln_k<4, false, true><<<512, 256, 0, stream>>>(pw, b2 + d * 512, x, x_hi, x_lo);
        }
    }

    // edge-final MLP: aebe via split-K x4 (64 blocks) + reduce, then fused per-edge kernel
    gemm2<128, true, false, false, false, false, false><<<dim3(2, 8, 4), 256, 0, stream>>>(
        x_hi, x_lo, eabt_h, eabt_l, nullptr, nullptr, nullptr, nullptr, nullptr, pw, 512, 128);
    redae_k<<<256, 256, 0, stream>>>(pw, eb1, aebe);
    edgemlp_k<<<(E + 15) / 16, 256, 0, stream>>>(ei, E, x, aebe, ect_h, ect_l,
                                                 ew2, eb2, ew3, eb3, P);
    final_k<<<256, 256, 0, stream>>>(tsym, P, (float*)d_out);
}

// Round 9
// 343.202 us; speedup vs baseline: 1.0308x; 1.0308x over previous
//
#include <hip/hip_runtime.h>
#include <hip/hip_bf16.h>
#include <math.h>

typedef __attribute__((ext_vector_type(8))) short bf16x8;
typedef __attribute__((ext_vector_type(4))) float f32x4;
typedef unsigned short u16;

__device__ __forceinline__ float gelu_f(float x) {
    float x3 = x * x * x;
    return 0.5f * x * (1.0f + tanhf(0.7978845608028654f * (x + 0.044715f * x3)));
}
__device__ __forceinline__ void bf_split(float v, u16& hi, u16& lo) {
    __hip_bfloat16 h = __float2bfloat16(v);
    hi = *(u16*)&h;
    float r = v - __bfloat162float(h);
    __hip_bfloat16 l = __float2bfloat16(r);
    lo = *(u16*)&l;
}

// ---------------- fused tsym + x0 + LN (+ tsym store), one row per block ----------------
__global__ __launch_bounds__(256) void x0row_k(const float* __restrict__ topo,
                                               const float* __restrict__ weight,
                                               const float* __restrict__ w_topo,
                                               const float* __restrict__ b_topo,
                                               const float* __restrict__ w_w,
                                               const float* __restrict__ b_w,
                                               const float* __restrict__ n_emb,
                                               float* __restrict__ tsym,
                                               float* __restrict__ x,
                                               u16* __restrict__ hhi, u16* __restrict__ hlo) {
    int bn = blockIdx.x;                 // 0..511
    int b = bn >> 7, n = bn & 127;
    int tid = threadIdx.x;
    __shared__ float tsr[128];
    __shared__ float red[256];
    if (tid < 128) {
        float v = topo[bn * 128 + tid] + topo[(b << 14) + (tid << 7) + n];
        tsr[tid] = v;
        tsym[bn * 128 + tid] = v;
    }
    __syncthreads();
    int c0 = tid, c1 = tid + 256;
    float acc0 = 0.f, acc1 = 0.f;
#pragma unroll 4
    for (int m = 0; m < 128; ++m) {
        float t = tsr[m];
        acc0 += t * w_topo[m * 512 + c0];
        acc1 += t * w_topo[m * 512 + c1];
    }
    float wgt = weight[bn];
    float v0 = acc0 + b_topo[c0] + wgt * w_w[c0] + b_w[c0] + n_emb[n * 512 + c0];
    float v1 = acc1 + b_topo[c1] + wgt * w_w[c1] + b_w[c1] + n_emb[n * 512 + c1];
    x[bn * 512 + c0] = v0;
    x[bn * 512 + c1] = v1;
    red[tid] = v0 + v1;
    __syncthreads();
    for (int off = 128; off > 0; off >>= 1) { if (tid < off) red[tid] += red[tid + off]; __syncthreads(); }
    float mean = red[0] * (1.0f / 512.0f);
    __syncthreads();
    float d0 = v0 - mean, d1 = v1 - mean;
    red[tid] = d0 * d0 + d1 * d1;
    __syncthreads();
    for (int off = 128; off > 0; off >>= 1) { if (tid < off) red[tid] += red[tid + off]; __syncthreads(); }
    float rs = rsqrtf(red[0] * (1.0f / 512.0f) + 1e-6f);
    u16 h, l;
    bf_split(d0 * rs, h, l); hhi[bn * 512 + c0] = h; hlo[bn * 512 + c0] = l;
    bf_split(d1 * rs, h, l); hhi[bn * 512 + c1] = h; hlo[bn * 512 + c1] = l;
}

// ---------------- weight transpose + bf16-split prep ----------------
__global__ __launch_bounds__(256) void prep_k(
    const float* __restrict__ wq, const float* __restrict__ wk, const float* __restrict__ wv,
    const float* __restrict__ wo, const float* __restrict__ w1, const float* __restrict__ w2,
    const float* __restrict__ ew1,
    u16* __restrict__ qkvt_h, u16* __restrict__ qkvt_l,
    u16* __restrict__ wot_h, u16* __restrict__ wot_l,
    u16* __restrict__ w1t_h, u16* __restrict__ w1t_l,
    u16* __restrict__ w2t_h, u16* __restrict__ w2t_l,
    u16* __restrict__ eabt_h, u16* __restrict__ eabt_l,
    u16* __restrict__ ect_h, u16* __restrict__ ect_l) {
    __shared__ u16 Hs[64][68];
    __shared__ u16 Ls[64][68];
    int bid = blockIdx.x;
    int region, tr, KK;
    u16 *dh, *dl;
    if (bid < 768)       { region = 0; tr = bid;        KK = 512;  dh = qkvt_h; dl = qkvt_l; }
    else if (bid < 1024) { region = 1; tr = bid - 768;  KK = 512;  dh = wot_h;  dl = wot_l; }
    else if (bid < 2048) { region = 2; tr = bid - 1024; KK = 512;  dh = w1t_h;  dl = w1t_l; }
    else if (bid < 3072) { region = 3; tr = bid - 2048; KK = 2048; dh = w2t_h;  dl = w2t_l; }
    else if (bid < 3088) { region = 4; tr = bid - 3072; KK = 512;  dh = eabt_h; dl = eabt_l; }
    else                 { region = 5; tr = bid - 3088; KK = 512;  dh = ect_h;  dl = ect_l; }
    int ktiles = KK >> 6;
    int tn = tr / ktiles, tk = tr % ktiles;
    int k0 = tk * 64, n0g = tn * 64;
    int tid = threadIdx.x;
#pragma unroll
    for (int p = 0; p < 4; ++p) {
        int kk = p * 16 + (tid >> 4);
        int nn = (tid & 15) * 4;
        int kg = k0 + kk, ng = n0g + nn;
        const float* src;
        if (region == 0) {
            int d = ng / 1536; int nr = ng - d * 1536; int sel = nr >> 9; int nc = nr & 511;
            const float* w = sel == 0 ? wq : (sel == 1 ? wk : wv);
            src = w + ((size_t)(d * 512 + kg)) * 512 + nc;
        } else if (region == 1) {
            int d = ng >> 9; int nc = ng & 511;
            src = wo + ((size_t)(d * 512 + kg)) * 512 + nc;
        } else if (region == 2) {
            int d = ng >> 11; int nc = ng & 2047;
            src = w1 + ((size_t)(d * 512 + kg)) * 2048 + nc;
        } else if (region == 3) {
            int d = ng >> 9; int nc = ng & 511;
            src = w2 + ((size_t)(d * 2048 + kg)) * 512 + nc;
        } else if (region == 4) {
            src = (ng < 64) ? (ew1 + (size_t)kg * 64 + ng) : (ew1 + (size_t)(512 + kg) * 64 + (ng - 64));
        } else {
            src = ew1 + (size_t)(1024 + kg) * 64 + ng;
        }
        float4 v = *(const float4*)src;
        u16 h0, l0, h1, l1, h2, l2, h3, l3;
        bf_split(v.x, h0, l0); bf_split(v.y, h1, l1);
        bf_split(v.z, h2, l2); bf_split(v.w, h3, l3);
        *(ushort4*)&Hs[kk][nn] = make_ushort4(h0, h1, h2, h3);
        *(ushort4*)&Ls[kk][nn] = make_ushort4(l0, l1, l2, l3);
    }
    __syncthreads();
#pragma unroll
    for (int p = 0; p < 2; ++p) {
        int chunk = p * 256 + tid;
        int nl = chunk >> 3;
        int k8 = (chunk & 7) * 8;
        ushort4 ha, hb, la, lb;
        ha.x = Hs[k8 + 0][nl]; ha.y = Hs[k8 + 1][nl]; ha.z = Hs[k8 + 2][nl]; ha.w = Hs[k8 + 3][nl];
        hb.x = Hs[k8 + 4][nl]; hb.y = Hs[k8 + 5][nl]; hb.z = Hs[k8 + 6][nl]; hb.w = Hs[k8 + 7][nl];
        la.x = Ls[k8 + 0][nl]; la.y = Ls[k8 + 1][nl]; la.z = Ls[k8 + 2][nl]; la.w = Ls[k8 + 3][nl];
        lb.x = Ls[k8 + 4][nl]; lb.y = Ls[k8 + 5][nl]; lb.z = Ls[k8 + 6][nl]; lb.w = Ls[k8 + 7][nl];
        size_t dst = (size_t)(n0g + nl) * KK + k0 + k8;
        *(ushort4*)(dh + dst) = ha; *(ushort4*)(dh + dst + 4) = hb;
        *(ushort4*)(dl + dst) = la; *(ushort4*)(dl + dst + 4) = lb;
    }
}

// ---------------- LDS-staged double-buffered split-bf16 MFMA GEMM ----------------
template <int KC, bool PARTIAL, bool GELU, bool RES, bool OUTF, bool OUTS, bool EBIAS>
__global__ __launch_bounds__(256) void gemm2(
    const u16* __restrict__ Ahi, const u16* __restrict__ Alo,
    const u16* __restrict__ Whi, const u16* __restrict__ Wlo,
    const float* __restrict__ bias, const float* __restrict__ Rres,
    float* __restrict__ C, u16* __restrict__ Chi, u16* __restrict__ Clo,
    float* __restrict__ part, int lda, int N) {
    __shared__ u16 sbuf[2][2][64][64];  // [buf][A/B][row][hi32|lo32]
    const int tid = threadIdx.x;
    const int l = tid & 63;
    const int w = tid >> 6;
    const int bn0 = blockIdx.x * 64;
    const int bm0 = blockIdx.y * 64;
    const int z = blockIdx.z;

    const u16* gp[4];
#pragma unroll
    for (int i = 0; i < 4; ++i) {
        int o = (i * 4 + w) * 1024 + l * 16;
        int mat = o >> 13;
        int r = (o >> 7) & 63;
        int slot = (o >> 4) & 7;
        int lslot = slot ^ (r & 7);
        int sel = lslot >> 2;
        int kel = (lslot & 3) * 8;
        const u16* basep;
        if (mat == 0) basep = (sel ? Alo : Ahi) + (size_t)(bm0 + r) * lda;
        else          basep = (sel ? Wlo : Whi) + (size_t)(bn0 + r) * lda;
        gp[i] = basep + kel + z * KC;
    }

    f32x4 acc[2][2] = {};
    constexpr int S = KC / 32;

    auto stage = [&](int buf, int ko) {
#pragma unroll
        for (int i = 0; i < 4; ++i) {
            __builtin_amdgcn_global_load_lds(
                (const __attribute__((address_space(1))) void*)(gp[i] + ko),
                (__attribute__((address_space(3))) void*)((char*)&sbuf[buf][0][0][0] + (i * 4 + w) * 1024),
                16, 0, 0);
        }
    };
    auto compute = [&](int buf) {
        bf16x8 a[2][2], b[2][2];
        int rA0 = (w & 1) * 32 + (l & 15);
        int rB0 = (w >> 1) * 32 + (l & 15);
        int lsl = l >> 4;
#pragma unroll
        for (int f = 0; f < 2; ++f) {
            int rA = rA0 + f * 16;
            int rB = rB0 + f * 16;
#pragma unroll
            for (int sel = 0; sel < 2; ++sel) {
                int psA = (lsl + sel * 4) ^ (rA & 7);
                int psB = (lsl + sel * 4) ^ (rB & 7);
                a[f][sel] = *(const bf16x8*)&sbuf[buf][0][rA][psA * 8];
                b[f][sel] = *(const bf16x8*)&sbuf[buf][1][rB][psB * 8];
            }
        }
#pragma unroll
        for (int fm = 0; fm < 2; ++fm)
#pragma unroll
            for (int fn = 0; fn < 2; ++fn) {
                acc[fm][fn] = __builtin_amdgcn_mfma_f32_16x16x32_bf16(a[fm][0], b[fn][0], acc[fm][fn], 0, 0, 0);
                acc[fm][fn] = __builtin_amdgcn_mfma_f32_16x16x32_bf16(a[fm][0], b[fn][1], acc[fm][fn], 0, 0, 0);
                acc[fm][fn] = __builtin_amdgcn_mfma_f32_16x16x32_bf16(a[fm][1], b[fn][0], acc[fm][fn], 0, 0, 0);
            }
    };

    stage(0, 0);
    __syncthreads();
#pragma unroll
    for (int s = 0; s < S; ++s) {
        if (s + 1 < S) stage((s + 1) & 1, (s + 1) * 32);
        compute(s & 1);
        __syncthreads();
    }

    int rb = bm0 + (w & 1) * 32 + (l >> 4) * 4;
    int cb = bn0 + (w >> 1) * 32 + (l & 15);
#pragma unroll
    for (int fm = 0; fm < 2; ++fm)
#pragma unroll
        for (int fn = 0; fn < 2; ++fn) {
            int col = cb + fn * 16;
            float bv;
            if (PARTIAL) bv = 0.f;
            else if (EBIAS) bv = col < 64 ? bias[col] : 0.f;
            else bv = bias[col];
#pragma unroll
            for (int r = 0; r < 4; ++r) {
                int row = rb + fm * 16 + r;
                float v = acc[fm][fn][r] + bv;
                if (PARTIAL) {
                    part[(size_t)z * 512 * N + (size_t)row * N + col] = v;
                } else {
                    if (GELU) v = gelu_f(v);
                    if (RES) v += Rres[(size_t)row * N + col];
                    if (OUTF) C[(size_t)row * N + col] = v;
                    if (OUTS) {
                        u16 h, lo2; bf_split(v, h, lo2);
                        Chi[(size_t)row * N + col] = h; Clo[(size_t)row * N + col] = lo2;
                    }
                }
            }
        }
}

// ---------------- split-K reduce + bias + residual -> x, then LN (or raw split) ----------------
template <int NZ, bool DOLN, bool DOSPLITX>
__global__ __launch_bounds__(256) void redln_k(const float* __restrict__ part,
                                               const float* __restrict__ bias,
                                               float* __restrict__ x,
                                               u16* __restrict__ hhi, u16* __restrict__ hlo) {
    int row = blockIdx.x;
    int tid = threadIdx.x;
    int c0 = tid, c1 = tid + 256;
    float v0 = bias[c0], v1 = bias[c1];
#pragma unroll
    for (int z = 0; z < NZ; ++z) {
        v0 += part[(size_t)z * 262144 + row * 512 + c0];
        v1 += part[(size_t)z * 262144 + row * 512 + c1];
    }
    v0 += x[row * 512 + c0];
    v1 += x[row * 512 + c1];
    x[row * 512 + c0] = v0;
    x[row * 512 + c1] = v1;
    u16 h, l;
    if (DOSPLITX) {
        bf_split(v0, h, l); hhi[row * 512 + c0] = h; hlo[row * 512 + c0] = l;
        bf_split(v1, h, l); hhi[row * 512 + c1] = h; hlo[row * 512 + c1] = l;
    }
    if (DOLN) {
        __shared__ float red[256];
        red[tid] = v0 + v1;
        __syncthreads();
        for (int off = 128; off > 0; off >>= 1) { if (tid < off) red[tid] += red[tid + off]; __syncthreads(); }
        float mean = red[0] * (1.0f / 512.0f);
        __syncthreads();
        float d0 = v0 - mean, d1 = v1 - mean;
        red[tid] = d0 * d0 + d1 * d1;
        __syncthreads();
        for (int off = 128; off > 0; off >>= 1) { if (tid < off) red[tid] += red[tid + off]; __syncthreads(); }
        float rs = rsqrtf(red[0] * (1.0f / 512.0f) + 1e-6f);
        bf_split(d0 * rs, h, l); hhi[row * 512 + c0] = h; hlo[row * 512 + c0] = l;
        bf_split(d1 * rs, h, l); hhi[row * 512 + c1] = h; hlo[row * 512 + c1] = l;
    }
}

// ---------------- fused masked attention; reads QKV split-K partials + biases directly ----------------
__global__ __launch_bounds__(256) void attn_k(const float* __restrict__ pw,
                                              const float* __restrict__ bq,
                                              const float* __restrict__ bk,
                                              const float* __restrict__ bv,
                                              const float* __restrict__ tsym,
                                              u16* __restrict__ agghi, u16* __restrict__ agglo) {
    int tt = blockIdx.x, hh = blockIdx.y, b = blockIdx.z;
    __shared__ __align__(16) float Ks[128 * 68];
    __shared__ __align__(16) float Vt[64 * 132];
    __shared__ __align__(16) float Ss[16 * 132];
    __shared__ __align__(16) float Qs[16][68];
    int tid = threadIdx.x;
    {
        int j = tid >> 1, c0 = (tid & 1) * 32;
        const float* kr0 = pw + (size_t)(b * 128 + j) * 1536 + 512 + hh * 64 + c0;
        const float* kr1 = kr0 + 786432;
        const float* bkp = bk + hh * 64 + c0;
        const float* bvp = bv + hh * 64 + c0;
#pragma unroll
        for (int c = 0; c < 32; c += 4) {
            float4 k0v = *(const float4*)(kr0 + c);
            float4 k1v = *(const float4*)(kr1 + c);
            float4 v0v = *(const float4*)(kr0 + 512 + c);
            float4 v1v = *(const float4*)(kr1 + 512 + c);
            float4 bkv = *(const float4*)(bkp + c);
            float4 bvv = *(const float4*)(bvp + c);
            Ks[j * 68 + c0 + c + 0] = k0v.x + k1v.x + bkv.x;
            Ks[j * 68 + c0 + c + 1] = k0v.y + k1v.y + bkv.y;
            Ks[j * 68 + c0 + c + 2] = k0v.z + k1v.z + bkv.z;
            Ks[j * 68 + c0 + c + 3] = k0v.w + k1v.w + bkv.w;
            Vt[(c0 + c + 0) * 132 + j] = v0v.x + v1v.x + bvv.x;
            Vt[(c0 + c + 1) * 132 + j] = v0v.y + v1v.y + bvv.y;
            Vt[(c0 + c + 2) * 132 + j] = v0v.z + v1v.z + bvv.z;
            Vt[(c0 + c + 3) * 132 + j] = v0v.w + v1v.w + bvv.w;
        }
    }
    {
        int rid = tid >> 4, c4 = (tid & 15) * 4;
        int grow = b * 128 + tt * 16 + rid;
        const float* q0 = pw + (size_t)grow * 1536 + hh * 64 + c4;
        float4 a = *(const float4*)q0;
        float4 a1 = *(const float4*)(q0 + 786432);
        float4 bb = *(const float4*)(bq + hh * 64 + c4);
        Qs[rid][c4 + 0] = a.x + a1.x + bb.x;
        Qs[rid][c4 + 1] = a.y + a1.y + bb.y;
        Qs[rid][c4 + 2] = a.z + a1.z + bb.z;
        Qs[rid][c4 + 3] = a.w + a1.w + bb.w;
    }
    __syncthreads();
    {
        int j = tid & 127, th = tid >> 7;
        float acc[8] = {0.f, 0.f, 0.f, 0.f, 0.f, 0.f, 0.f, 0.f};
        for (int d0 = 0; d0 < 64; d0 += 4) {
            float4 kv = *(const float4*)&Ks[j * 68 + d0];
#pragma unroll
            for (int r = 0; r < 8; ++r) {
                float4 qv = *(const float4*)&Qs[th * 8 + r][d0];
                acc[r] += qv.x * kv.x + qv.y * kv.y + qv.z * kv.z + qv.w * kv.w;
            }
        }
        const float* tsr = tsym + ((size_t)b << 14) + (size_t)(tt * 16 + th * 8) * 128 + j;
#pragma unroll
        for (int r = 0; r < 8; ++r) {
            int t = th * 8 + r;
            float sv = (tsr[r * 128] > 0.f) ? acc[r] * 0.125f : -INFINITY;
            Ss[t * 132 + j] = sv;
        }
    }
    __syncthreads();
    {
        int row = tid >> 4, l16 = tid & 15;
        float v[8]; float m = -INFINITY;
#pragma unroll
        for (int c = 0; c < 8; ++c) { v[c] = Ss[row * 132 + l16 + c * 16]; m = fmaxf(m, v[c]); }
#pragma unroll
        for (int off = 8; off; off >>= 1) m = fmaxf(m, __shfl_xor(m, off));
        float ssum = 0.f;
#pragma unroll
        for (int c = 0; c < 8; ++c) {
            float e = (v[c] == -INFINITY) ? 0.f : __expf(v[c] - m);
            v[c] = e; ssum += e;
        }
#pragma unroll
        for (int off = 8; off; off >>= 1) ssum += __shfl_xor(ssum, off);
        float inv = 1.0f / (ssum + 1e-12f);
#pragma unroll
        for (int c = 0; c < 8; ++c) Ss[row * 132 + l16 + c * 16] = v[c] * inv;
    }
    __syncthreads();
    {
        int d = tid & 63, tq = tid >> 6;
        float a0 = 0.f, a1 = 0.f, a2 = 0.f, a3 = 0.f;
        for (int j0 = 0; j0 < 128; j0 += 4) {
            float4 vv = *(const float4*)&Vt[d * 132 + j0];
            float4 s0 = *(const float4*)&Ss[(tq * 4 + 0) * 132 + j0];
            float4 s1 = *(const float4*)&Ss[(tq * 4 + 1) * 132 + j0];
            float4 s2 = *(const float4*)&Ss[(tq * 4 + 2) * 132 + j0];
            float4 s3 = *(const float4*)&Ss[(tq * 4 + 3) * 132 + j0];
            a0 += s0.x * vv.x + s0.y * vv.y + s0.z * vv.z + s0.w * vv.w;
            a1 += s1.x * vv.x + s1.y * vv.y + s1.z * vv.z + s1.w * vv.w;
            a2 += s2.x * vv.x + s2.y * vv.y + s2.z * vv.z + s2.w * vv.w;
            a3 += s3.x * vv.x + s3.y * vv.y + s3.z * vv.z + s3.w * vv.w;
        }
        float accv[4] = {a0, a1, a2, a3};
        int growbase = b * 128 + tt * 16;
#pragma unroll
        for (int i = 0; i < 4; ++i) {
            int t = tq * 4 + i;
            u16 h, l; bf_split(accv[i], h, l);
            size_t o = (size_t)(growbase + t) * 512 + hh * 64 + d;
            agghi[o] = h; agglo[o] = l;
        }
    }
}

// ---------------- aebe reduce (inline concat bias) ----------------
__global__ __launch_bounds__(256) void redae_k(const float* __restrict__ part,
                                               const float* __restrict__ eb1,
                                               float* __restrict__ aebe) {
    int idx = blockIdx.x * 256 + threadIdx.x;   // 512*128
    int col = idx & 127;
    float v = col < 64 ? eb1[col] : 0.0f;
#pragma unroll
    for (int z = 0; z < 4; ++z) v += part[(size_t)z * 65536 + idx];
    aebe[idx] = v;
}

// ---------------- dense cross-term GEMM: C3[b,i,j,o] = ((x[b,i]*x[b,j]) @ W1c)[o], all pairs ----------------
// One block per (i, b). M=128(j) x N=64(o), K=512. A built on the fly (VALU product+split ->
// XOR-swizzled LDS, both write & read sides controlled), B (ect) read directly from L2.
__global__ __launch_bounds__(256) void cross_k(const float* __restrict__ x,
                                               const u16* __restrict__ ect_h,
                                               const u16* __restrict__ ect_l,
                                               float* __restrict__ C3) {
    int i = blockIdx.x, b = blockIdx.y;
    __shared__ float xis[512];
    __shared__ u16 As[2][128][64];   // [buf][row j][hi k0..31 | lo k0..31], slots XOR-swizzled
    int tid = threadIdx.x;
    {
        const float* xip = x + (size_t)(b * 128 + i) * 512;
        xis[tid] = xip[tid];
        xis[tid + 256] = xip[tid + 256];
    }
    // A-staging mapping: thread -> (row, k-half)
    int r = tid >> 1, half = tid & 1, koff = half * 16;
    const float* xr = x + (size_t)(b * 128 + r) * 512 + koff;
    int r7 = r & 7;
    // fragment mapping: wave w -> m-half, n-half
    int lane = tid & 63, w = tid >> 6;
    int m0 = (w & 1) * 64, n0 = (w >> 1) * 32;
    int l15 = lane & 15, lsl = lane >> 4, kf = lsl * 8;
    const u16* pBh0 = ect_h + (size_t)(n0 + l15) * 512 + kf;
    const u16* pBl0 = ect_l + (size_t)(n0 + l15) * 512 + kf;
    const u16* pBh1 = ect_h + (size_t)(n0 + 16 + l15) * 512 + kf;
    const u16* pBl1 = ect_l + (size_t)(n0 + 16 + l15) * 512 + kf;
    f32x4 acc[4][2] = {};

    auto stageA = [&](int buf, int kbase) {
        float4 v0 = *(const float4*)(xr + kbase);
        float4 v1 = *(const float4*)(xr + kbase + 4);
        float4 v2 = *(const float4*)(xr + kbase + 8);
        float4 v3 = *(const float4*)(xr + kbase + 12);
        float xv[16] = {v0.x, v0.y, v0.z, v0.w, v1.x, v1.y, v1.z, v1.w,
                        v2.x, v2.y, v2.z, v2.w, v3.x, v3.y, v3.z, v3.w};
        bf16x8 h0, h1, l0v, l1v;
#pragma unroll
        for (int q = 0; q < 8; ++q) {
            u16 hh, ll; bf_split(xv[q] * xis[kbase + koff + q], hh, ll);
            h0[q] = (short)hh; l0v[q] = (short)ll;
        }
#pragma unroll
        for (int q = 0; q < 8; ++q) {
            u16 hh, ll; bf_split(xv[8 + q] * xis[kbase + koff + 8 + q], hh, ll);
            h1[q] = (short)hh; l1v[q] = (short)ll;
        }
        *(bf16x8*)&As[buf][r][((2 * half + 0) ^ r7) * 8] = h0;
        *(bf16x8*)&As[buf][r][((2 * half + 1) ^ r7) * 8] = h1;
        *(bf16x8*)&As[buf][r][((4 + 2 * half + 0) ^ r7) * 8] = l0v;
        *(bf16x8*)&As[buf][r][((4 + 2 * half + 1) ^ r7) * 8] = l1v;
    };
    auto compute = [&](int buf, int kbase) {
        bf16x8 bh0 = *(const bf16x8*)(pBh0 + kbase);
        bf16x8 bl0 = *(const bf16x8*)(pBl0 + kbase);
        bf16x8 bh1 = *(const bf16x8*)(pBh1 + kbase);
        bf16x8 bl1 = *(const bf16x8*)(pBl1 + kbase);
#pragma unroll
        for (int mf = 0; mf < 4; ++mf) {
            int rA = m0 + mf * 16 + l15;
            int ra7 = rA & 7;
            bf16x8 ah = *(const bf16x8*)&As[buf][rA][(lsl ^ ra7) * 8];
            bf16x8 al = *(const bf16x8*)&As[buf][rA][((4 + lsl) ^ ra7) * 8];
            acc[mf][0] = __builtin_amdgcn_mfma_f32_16x16x32_bf16(ah, bh0, acc[mf][0], 0, 0, 0);
            acc[mf][0] = __builtin_amdgcn_mfma_f32_16x16x32_bf16(ah, bl0, acc[mf][0], 0, 0, 0);
            acc[mf][0] = __builtin_amdgcn_mfma_f32_16x16x32_bf16(al, bh0, acc[mf][0], 0, 0, 0);
            acc[mf][1] = __builtin_amdgcn_mfma_f32_16x16x32_bf16(ah, bh1, acc[mf][1], 0, 0, 0);
            acc[mf][1] = __builtin_amdgcn_mfma_f32_16x16x32_bf16(ah, bl1, acc[mf][1], 0, 0, 0);
            acc[mf][1] = __builtin_amdgcn_mfma_f32_16x16x32_bf16(al, bh1, acc[mf][1], 0, 0, 0);
        }
    };

    __syncthreads();           // xis ready
    stageA(0, 0);
    __syncthreads();
    for (int s = 0; s < 16; ++s) {
        if (s < 15) stageA((s + 1) & 1, (s + 1) * 32);
        compute(s & 1, s * 32);
        __syncthreads();
    }

    float* outp = C3 + (size_t)(b * 128 + i) * 128 * 64;
#pragma unroll
    for (int mf = 0; mf < 4; ++mf)
#pragma unroll
        for (int nf = 0; nf < 2; ++nf)
#pragma unroll
            for (int q = 0; q < 4; ++q)
                outp[(size_t)(m0 + mf * 16 + lsl * 4 + q) * 64 + (n0 + nf * 16 + l15)] = acc[mf][nf][q];
}

// ---------------- per-edge finish: gelu(C3+ae+be) -> layer2 -> layer3 -> sigmoid ----------------
__global__ __launch_bounds__(256) void efin_k(const int* __restrict__ ei, int E,
                                              const float* __restrict__ C3,
                                              const float* __restrict__ aebe,
                                              const float* __restrict__ ew2, const float* __restrict__ eb2,
                                              const float* __restrict__ ew3, const float* __restrict__ eb3,
                                              float* __restrict__ P) {
    __shared__ float G1[32][66];
    __shared__ float G2[32][66];
    __shared__ int s_src[32], s_dst[32];
    int tid = threadIdx.x;
    int e0 = blockIdx.x * 32;
    if (tid < 32) {
        int e = e0 + tid;
        s_src[tid] = e < E ? ei[e] : 0;
        s_dst[tid] = e < E ? ei[E + e] : 0;
    }
    __syncthreads();
    {
        int e = tid >> 3, c8 = (tid & 7) * 8;
        int s = s_src[e], d = s_dst[e];
        int bB = s >> 7, i2 = s & 127, j2 = d & 127;
        const float* c3 = C3 + ((size_t)(bB * 128 + i2) * 128 + j2) * 64 + c8;
        const float* ap = aebe + (size_t)s * 128 + c8;
        const float* bp = aebe + (size_t)d * 128 + 64 + c8;
#pragma unroll
        for (int q = 0; q < 8; ++q)
            G1[e][c8 + q] = gelu_f(c3[q] + ap[q] + bp[q]);
    }
    __syncthreads();
    {
        int col = tid & 63, eq = tid >> 6;
        float acc[8];
#pragma unroll
        for (int i = 0; i < 8; ++i) acc[i] = eb2[col];
        for (int m = 0; m < 64; ++m) {
            float wv = ew2[m * 64 + col];
#pragma unroll
            for (int i = 0; i < 8; ++i) acc[i] += G1[eq * 8 + i][m] * wv;
        }
#pragma unroll
        for (int i = 0; i < 8; ++i) G2[eq * 8 + i][col] = gelu_f(acc[i]);
    }
    __syncthreads();
    {
        int el2 = tid >> 3, c8 = (tid & 7) * 8;
        float p = 0.f;
#pragma unroll
        for (int i = 0; i < 8; ++i) p += G2[el2][c8 + i] * ew3[c8 + i];
        p += __shfl_xor(p, 1); p += __shfl_xor(p, 2); p += __shfl_xor(p, 4);
        if ((tid & 7) == 0 && e0 + el2 < E) {
            float logit = p + eb3[0];
            int s = s_src[el2], d2 = s_dst[el2];
            int bB = s >> 7, i2 = s & 127, j2 = d2 & 127;
            P[(bB << 14) + (i2 << 7) + j2] = 1.0f / (1.0f + expf(-logit));
        }
    }
}

// ---------------- final symmetrize + mask ----------------
__global__ __launch_bounds__(256) void final_k(const float* __restrict__ tsym,
                                               const float* __restrict__ P,
                                               float* __restrict__ out) {
    int idx = blockIdx.x * 256 + threadIdx.x;
    int b = idx >> 14, i = (idx >> 7) & 127, j = idx & 127;
    float o = 0.0f;
    if (i != j && tsym[idx] > 0.0f)
        o = 0.5f * (P[idx] + P[(b << 14) + (j << 7) + i]);
    out[idx] = o;
}

extern "C" void kernel_launch(void* const* d_in, const int* in_sizes, int n_in,
                              void* d_out, int out_size, void* d_ws, size_t ws_size,
                              hipStream_t stream) {
    const float* topo   = (const float*)d_in[0];
    const float* weight = (const float*)d_in[1];
    const int*   ei     = (const int*)d_in[2];
    const float* w_topo = (const float*)d_in[3];
    const float* b_topo = (const float*)d_in[4];
    const float* w_w    = (const float*)d_in[5];
    const float* b_w    = (const float*)d_in[6];
    const float* n_emb  = (const float*)d_in[7];
    const float* wq = (const float*)d_in[8];  const float* bq = (const float*)d_in[9];
    const float* wk = (const float*)d_in[10]; const float* bk = (const float*)d_in[11];
    const float* wv = (const float*)d_in[12]; const float* bv = (const float*)d_in[13];
    const float* wo = (const float*)d_in[14]; const float* bo = (const float*)d_in[15];
    const float* w1 = (const float*)d_in[16]; const float* b1 = (const float*)d_in[17];
    const float* w2 = (const float*)d_in[18]; const float* b2 = (const float*)d_in[19];
    const float* ew1 = (const float*)d_in[20]; const float* eb1 = (const float*)d_in[21];
    const float* ew2 = (const float*)d_in[22]; const float* eb2 = (const float*)d_in[23];
    const float* ew3 = (const float*)d_in[24]; const float* eb3 = (const float*)d_in[25];
    const int E = in_sizes[2] / 2;

    char* base = (char*)d_ws;
    size_t off = 0;
    auto alloc = [&](size_t bytes) { char* p = base + off; off += (bytes + 255) & ~(size_t)255; return p; };
    u16* qkvt_h = (u16*)alloc(3145728 * 2); u16* qkvt_l = (u16*)alloc(3145728 * 2);
    u16* wot_h  = (u16*)alloc(1048576 * 2); u16* wot_l  = (u16*)alloc(1048576 * 2);
    u16* w1t_h  = (u16*)alloc(4194304 * 2); u16* w1t_l  = (u16*)alloc(4194304 * 2);
    u16* w2t_h  = (u16*)alloc(4194304 * 2); u16* w2t_l  = (u16*)alloc(4194304 * 2);
    u16* eabt_h = (u16*)alloc(65536 * 2);   u16* eabt_l = (u16*)alloc(65536 * 2);
    u16* ect_h  = (u16*)alloc(32768 * 2);   u16* ect_l  = (u16*)alloc(32768 * 2);
    u16* h_hi   = (u16*)alloc(262144 * 2);  u16* h_lo   = (u16*)alloc(262144 * 2);
    u16* agg_hi = (u16*)alloc(262144 * 2);  u16* agg_lo = (u16*)alloc(262144 * 2);
    u16* mid_hi = (u16*)alloc(1048576 * 2); u16* mid_lo = (u16*)alloc(1048576 * 2);
    u16* x_hi   = (u16*)alloc(262144 * 2);  u16* x_lo   = (u16*)alloc(262144 * 2);
    float* tsym  = (float*)alloc(65536 * 4);
    float* x     = (float*)alloc(262144 * 4);
    float* aebe  = (float*)alloc(65536 * 4);
    float* P     = (float*)alloc(65536 * 4);
    float* pw    = (float*)alloc(1572864 * 4);   // split-K partials (max: qkv 2x512x1536)
    float* C3    = (float*)alloc((size_t)16777216 * 4);  // dense cross term (B,N,N,64) = 67 MB

    prep_k<<<3096, 256, 0, stream>>>(wq, wk, wv, wo, w1, w2, ew1,
                                     qkvt_h, qkvt_l, wot_h, wot_l, w1t_h, w1t_l,
                                     w2t_h, w2t_l, eabt_h, eabt_l, ect_h, ect_l);
    x0row_k<<<512, 256, 0, stream>>>(topo, weight, w_topo, b_topo, w_w, b_w, n_emb,
                                     tsym, x, h_hi, h_lo);

    for (int d = 0; d < 4; ++d) {
        // QKV: split-K x2 -> partials; bias+reduce fused into attn
        gemm2<256, true, false, false, false, false, false><<<dim3(24, 8, 2), 256, 0, stream>>>(
            h_hi, h_lo, qkvt_h + (size_t)d * 1536 * 512, qkvt_l + (size_t)d * 1536 * 512,
            nullptr, nullptr, nullptr, nullptr, nullptr, pw, 512, 1536);
        attn_k<<<dim3(8, 8, 4), 256, 0, stream>>>(pw, bq + d * 512, bk + d * 512, bv + d * 512,
                                                  tsym, agg_hi, agg_lo);
        // WO: split-K x4 -> partials -> fused reduce+res+LN
        gemm2<128, true, false, false, false, false, false><<<dim3(8, 8, 4), 256, 0, stream>>>(
            agg_hi, agg_lo, wot_h + (size_t)d * 512 * 512, wot_l + (size_t)d * 512 * 512,
            nullptr, nullptr, nullptr, nullptr, nullptr, pw, 512, 512);
        redln_k<4, true, false><<<512, 256, 0, stream>>>(pw, bo + d * 512, x, h_hi, h_lo);
        // MLP1: full-K, gelu + split out
        gemm2<512, false, true, false, false, true, false><<<dim3(32, 8, 1), 256, 0, stream>>>(
            h_hi, h_lo, w1t_h + (size_t)d * 2048 * 512, w1t_l + (size_t)d * 2048 * 512,
            b1 + d * 2048, nullptr, nullptr, mid_hi, mid_lo, nullptr, 512, 2048);
        // MLP2: split-K x4 -> partials -> fused reduce+res (+LN | +split)
        gemm2<512, true, false, false, false, false, false><<<dim3(8, 8, 4), 256, 0, stream>>>(
            mid_hi, mid_lo, w2t_h + (size_t)d * 512 * 2048, w2t_l + (size_t)d * 512 * 2048,
            nullptr, nullptr, nullptr, nullptr, nullptr, pw, 2048, 512);
        if (d < 3) {
            redln_k<4, true, false><<<512, 256, 0, stream>>>(pw, b2 + d * 512, x, h_hi, h_lo);
        } else {
            redln_k<4, false, true><<<512, 256, 0, stream>>>(pw, b2 + d * 512, x, x_hi, x_lo);
        }
    }

    // edge-final MLP: aebe via split-K x4 + reduce; dense cross GEMM; per-edge finish
    gemm2<128, true, false, false, false, false, false><<<dim3(2, 8, 4), 256, 0, stream>>>(
        x_hi, x_lo, eabt_h, eabt_l, nullptr, nullptr, nullptr, nullptr, nullptr, pw, 512, 128);
    redae_k<<<256, 256, 0, stream>>>(pw, eb1, aebe);
    cross_k<<<dim3(128, 4), 256, 0, stream>>>(x, ect_h, ect_l, C3);
    efin_k<<<(E + 31) / 32, 256, 0, stream>>>(ei, E, C3, aebe, ew2, eb2, ew3, eb3, P);
    final_k<<<256, 256, 0, stream>>>(tsym, P, (float*)d_out);
}

// Round 10
// 292.275 us; speedup vs baseline: 1.2104x; 1.1742x over previous
//
#include <hip/hip_runtime.h>
#include <hip/hip_bf16.h>
#include <math.h>

typedef __attribute__((ext_vector_type(8))) _Float16 f16x8;
typedef __attribute__((ext_vector_type(8))) short short8;
typedef __attribute__((ext_vector_type(4))) float f32x4;
typedef unsigned short u16;

__device__ __forceinline__ float gelu_f(float x) {
    float x3 = x * x * x;
    return 0.5f * x * (1.0f + tanhf(0.7978845608028654f * (x + 0.044715f * x3)));
}
__device__ __forceinline__ u16 f2h(float v) {
    _Float16 h = (_Float16)v;
    return *(u16*)&h;
}

// ---------------- fused tsym + x0 + LN (+ tsym store), one row per block ----------------
__global__ __launch_bounds__(256) void x0row_k(const float* __restrict__ topo,
                                               const float* __restrict__ weight,
                                               const float* __restrict__ w_topo,
                                               const float* __restrict__ b_topo,
                                               const float* __restrict__ w_w,
                                               const float* __restrict__ b_w,
                                               const float* __restrict__ n_emb,
                                               float* __restrict__ tsym,
                                               float* __restrict__ x,
                                               u16* __restrict__ h16) {
    int bn = blockIdx.x;                 // 0..511
    int b = bn >> 7, n = bn & 127;
    int tid = threadIdx.x;
    __shared__ float tsr[128];
    __shared__ float red[256];
    if (tid < 128) {
        float v = topo[bn * 128 + tid] + topo[(b << 14) + (tid << 7) + n];
        tsr[tid] = v;
        tsym[bn * 128 + tid] = v;
    }
    __syncthreads();
    int c0 = tid, c1 = tid + 256;
    float acc0 = 0.f, acc1 = 0.f;
#pragma unroll 4
    for (int m = 0; m < 128; ++m) {
        float t = tsr[m];
        acc0 += t * w_topo[m * 512 + c0];
        acc1 += t * w_topo[m * 512 + c1];
    }
    float wgt = weight[bn];
    float v0 = acc0 + b_topo[c0] + wgt * w_w[c0] + b_w[c0] + n_emb[n * 512 + c0];
    float v1 = acc1 + b_topo[c1] + wgt * w_w[c1] + b_w[c1] + n_emb[n * 512 + c1];
    x[bn * 512 + c0] = v0;
    x[bn * 512 + c1] = v1;
    red[tid] = v0 + v1;
    __syncthreads();
    for (int off = 128; off > 0; off >>= 1) { if (tid < off) red[tid] += red[tid + off]; __syncthreads(); }
    float mean = red[0] * (1.0f / 512.0f);
    __syncthreads();
    float d0 = v0 - mean, d1 = v1 - mean;
    red[tid] = d0 * d0 + d1 * d1;
    __syncthreads();
    for (int off = 128; off > 0; off >>= 1) { if (tid < off) red[tid] += red[tid + off]; __syncthreads(); }
    float rs = rsqrtf(red[0] * (1.0f / 512.0f) + 1e-6f);
    h16[bn * 512 + c0] = f2h(d0 * rs);
    h16[bn * 512 + c1] = f2h(d1 * rs);
}

// ---------------- weight transpose + fp16 prep ----------------
__global__ __launch_bounds__(256) void prep_k(
    const float* __restrict__ wq, const float* __restrict__ wk, const float* __restrict__ wv,
    const float* __restrict__ wo, const float* __restrict__ w1, const float* __restrict__ w2,
    const float* __restrict__ ew1,
    u16* __restrict__ qkvt, u16* __restrict__ wot,
    u16* __restrict__ w1t, u16* __restrict__ w2t,
    u16* __restrict__ eabt, u16* __restrict__ ect) {
    __shared__ u16 Hs[64][68];
    int bid = blockIdx.x;
    int region, tr, KK;
    u16* dh;
    if (bid < 768)       { region = 0; tr = bid;        KK = 512;  dh = qkvt; }
    else if (bid < 1024) { region = 1; tr = bid - 768;  KK = 512;  dh = wot; }
    else if (bid < 2048) { region = 2; tr = bid - 1024; KK = 512;  dh = w1t; }
    else if (bid < 3072) { region = 3; tr = bid - 2048; KK = 2048; dh = w2t; }
    else if (bid < 3088) { region = 4; tr = bid - 3072; KK = 512;  dh = eabt; }
    else                 { region = 5; tr = bid - 3088; KK = 512;  dh = ect; }
    int ktiles = KK >> 6;
    int tn = tr / ktiles, tk = tr % ktiles;
    int k0 = tk * 64, n0g = tn * 64;
    int tid = threadIdx.x;
#pragma unroll
    for (int p = 0; p < 4; ++p) {
        int kk = p * 16 + (tid >> 4);
        int nn = (tid & 15) * 4;
        int kg = k0 + kk, ng = n0g + nn;
        const float* src;
        if (region == 0) {
            int d = ng / 1536; int nr = ng - d * 1536; int sel = nr >> 9; int nc = nr & 511;
            const float* w = sel == 0 ? wq : (sel == 1 ? wk : wv);
            src = w + ((size_t)(d * 512 + kg)) * 512 + nc;
        } else if (region == 1) {
            int d = ng >> 9; int nc = ng & 511;
            src = wo + ((size_t)(d * 512 + kg)) * 512 + nc;
        } else if (region == 2) {
            int d = ng >> 11; int nc = ng & 2047;
            src = w1 + ((size_t)(d * 512 + kg)) * 2048 + nc;
        } else if (region == 3) {
            int d = ng >> 9; int nc = ng & 511;
            src = w2 + ((size_t)(d * 2048 + kg)) * 512 + nc;
        } else if (region == 4) {
            src = (ng < 64) ? (ew1 + (size_t)kg * 64 + ng) : (ew1 + (size_t)(512 + kg) * 64 + (ng - 64));
        } else {
            src = ew1 + (size_t)(1024 + kg) * 64 + ng;
        }
        float4 v = *(const float4*)src;
        *(ushort4*)&Hs[kk][nn] = make_ushort4(f2h(v.x), f2h(v.y), f2h(v.z), f2h(v.w));
    }
    __syncthreads();
#pragma unroll
    for (int p = 0; p < 2; ++p) {
        int chunk = p * 256 + tid;
        int nl = chunk >> 3;
        int k8 = (chunk & 7) * 8;
        ushort4 ha, hb;
        ha.x = Hs[k8 + 0][nl]; ha.y = Hs[k8 + 1][nl]; ha.z = Hs[k8 + 2][nl]; ha.w = Hs[k8 + 3][nl];
        hb.x = Hs[k8 + 4][nl]; hb.y = Hs[k8 + 5][nl]; hb.z = Hs[k8 + 6][nl]; hb.w = Hs[k8 + 7][nl];
        size_t dst = (size_t)(n0g + nl) * KK + k0 + k8;
        *(ushort4*)(dh + dst) = ha; *(ushort4*)(dh + dst + 4) = hb;
    }
}

// ---------------- LDS-staged double-buffered fp16 MFMA GEMM ----------------
// 64x64 tile, BK=32, 4 waves. LDS row = 32 fp16 = 64B = 4 slots of 16B,
// phys slot = logical slot ^ ((row>>1)&3) (applied on global source AND ds_read).
template <int KC, bool PARTIAL, bool GELU, bool RES, bool OUTF, bool OUTS, bool EBIAS>
__global__ __launch_bounds__(256) void gemm2(
    const u16* __restrict__ A16, const u16* __restrict__ W16,
    const float* __restrict__ bias, const float* __restrict__ Rres,
    float* __restrict__ C, u16* __restrict__ C16,
    float* __restrict__ part, int lda, int N) {
    __shared__ u16 sbuf[2][2][64][32];  // [buf][A/B][row][32 fp16]
    const int tid = threadIdx.x;
    const int l = tid & 63;
    const int w = tid >> 6;
    const int bn0 = blockIdx.x * 64;
    const int bm0 = blockIdx.y * 64;
    const int z = blockIdx.z;

    const u16* gp[2];
#pragma unroll
    for (int i = 0; i < 2; ++i) {
        int o = (i * 4 + w) * 1024 + l * 16;
        int mat = o >> 12;               // 0 = A, 1 = B
        int r = (o >> 6) & 63;
        int slot = (o >> 4) & 3;
        int lslot = slot ^ ((r >> 1) & 3);
        int kel = lslot * 8;
        const u16* basep = mat == 0 ? (A16 + (size_t)(bm0 + r) * lda)
                                    : (W16 + (size_t)(bn0 + r) * lda);
        gp[i] = basep + kel + z * KC;
    }

    f32x4 acc[2][2] = {};
    constexpr int S = KC / 32;

    auto stage = [&](int buf, int ko) {
#pragma unroll
        for (int i = 0; i < 2; ++i) {
            __builtin_amdgcn_global_load_lds(
                (const __attribute__((address_space(1))) void*)(gp[i] + ko),
                (__attribute__((address_space(3))) void*)((char*)&sbuf[buf][0][0][0] + (i * 4 + w) * 1024),
                16, 0, 0);
        }
    };
    auto compute = [&](int buf) {
        f16x8 a[2], b[2];
        int l15 = l & 15, lsl = l >> 4;
        int rA0 = (w & 1) * 32 + l15;
        int rB0 = (w >> 1) * 32 + l15;
#pragma unroll
        for (int f = 0; f < 2; ++f) {
            int rA = rA0 + f * 16;
            int rB = rB0 + f * 16;
            a[f] = *(const f16x8*)&sbuf[buf][0][rA][(lsl ^ ((rA >> 1) & 3)) * 8];
            b[f] = *(const f16x8*)&sbuf[buf][1][rB][(lsl ^ ((rB >> 1) & 3)) * 8];
        }
#pragma unroll
        for (int fm = 0; fm < 2; ++fm)
#pragma unroll
            for (int fn = 0; fn < 2; ++fn)
                acc[fm][fn] = __builtin_amdgcn_mfma_f32_16x16x32_f16(a[fm], b[fn], acc[fm][fn], 0, 0, 0);
    };

    stage(0, 0);
    __syncthreads();
#pragma unroll
    for (int s = 0; s < S; ++s) {
        if (s + 1 < S) stage((s + 1) & 1, (s + 1) * 32);
        compute(s & 1);
        __syncthreads();
    }

    int rb = bm0 + (w & 1) * 32 + ((l >> 4)) * 4;
    int cb = bn0 + (w >> 1) * 32 + (l & 15);
#pragma unroll
    for (int fm = 0; fm < 2; ++fm)
#pragma unroll
        for (int fn = 0; fn < 2; ++fn) {
            int col = cb + fn * 16;
            float bv;
            if (PARTIAL) bv = 0.f;
            else if (EBIAS) bv = col < 64 ? bias[col] : 0.f;
            else bv = bias[col];
#pragma unroll
            for (int r = 0; r < 4; ++r) {
                int row = rb + fm * 16 + r;
                float v = acc[fm][fn][r] + bv;
                if (PARTIAL) {
                    part[(size_t)z * 512 * N + (size_t)row * N + col] = v;
                } else {
                    if (GELU) v = gelu_f(v);
                    if (RES) v += Rres[(size_t)row * N + col];
                    if (OUTF) C[(size_t)row * N + col] = v;
                    if (OUTS) C16[(size_t)row * N + col] = f2h(v);
                }
            }
        }
}

// ---------------- split-K reduce + bias + residual -> x, then LN (or raw fp16) ----------------
template <int NZ, bool DOLN, bool DOSPLITX>
__global__ __launch_bounds__(256) void redln_k(const float* __restrict__ part,
                                               const float* __restrict__ bias,
                                               float* __restrict__ x,
                                               u16* __restrict__ h16) {
    int row = blockIdx.x;
    int tid = threadIdx.x;
    int c0 = tid, c1 = tid + 256;
    float v0 = bias[c0], v1 = bias[c1];
#pragma unroll
    for (int z = 0; z < NZ; ++z) {
        v0 += part[(size_t)z * 262144 + row * 512 + c0];
        v1 += part[(size_t)z * 262144 + row * 512 + c1];
    }
    v0 += x[row * 512 + c0];
    v1 += x[row * 512 + c1];
    x[row * 512 + c0] = v0;
    x[row * 512 + c1] = v1;
    if (DOSPLITX) {
        h16[row * 512 + c0] = f2h(v0);
        h16[row * 512 + c1] = f2h(v1);
    }
    if (DOLN) {
        __shared__ float red[256];
        red[tid] = v0 + v1;
        __syncthreads();
        for (int off = 128; off > 0; off >>= 1) { if (tid < off) red[tid] += red[tid + off]; __syncthreads(); }
        float mean = red[0] * (1.0f / 512.0f);
        __syncthreads();
        float d0 = v0 - mean, d1 = v1 - mean;
        red[tid] = d0 * d0 + d1 * d1;
        __syncthreads();
        for (int off = 128; off > 0; off >>= 1) { if (tid < off) red[tid] += red[tid + off]; __syncthreads(); }
        float rs = rsqrtf(red[0] * (1.0f / 512.0f) + 1e-6f);
        h16[row * 512 + c0] = f2h(d0 * rs);
        h16[row * 512 + c1] = f2h(d1 * rs);
    }
}

// ---------------- fused masked attention; reads QKV split-K partials + biases directly ----------------
__global__ __launch_bounds__(256) void attn_k(const float* __restrict__ pw,
                                              const float* __restrict__ bq,
                                              const float* __restrict__ bk,
                                              const float* __restrict__ bv,
                                              const float* __restrict__ tsym,
                                              u16* __restrict__ agg16) {
    int tt = blockIdx.x, hh = blockIdx.y, b = blockIdx.z;
    __shared__ __align__(16) float Ks[128 * 68];
    __shared__ __align__(16) float Vt[64 * 132];
    __shared__ __align__(16) float Ss[16 * 132];
    __shared__ __align__(16) float Qs[16][68];
    int tid = threadIdx.x;
    {
        int j = tid >> 1, c0 = (tid & 1) * 32;
        const float* kr0 = pw + (size_t)(b * 128 + j) * 1536 + 512 + hh * 64 + c0;
        const float* kr1 = kr0 + 786432;
        const float* bkp = bk + hh * 64 + c0;
        const float* bvp = bv + hh * 64 + c0;
#pragma unroll
        for (int c = 0; c < 32; c += 4) {
            float4 k0v = *(const float4*)(kr0 + c);
            float4 k1v = *(const float4*)(kr1 + c);
            float4 v0v = *(const float4*)(kr0 + 512 + c);
            float4 v1v = *(const float4*)(kr1 + 512 + c);
            float4 bkv = *(const float4*)(bkp + c);
            float4 bvv = *(const float4*)(bvp + c);
            Ks[j * 68 + c0 + c + 0] = k0v.x + k1v.x + bkv.x;
            Ks[j * 68 + c0 + c + 1] = k0v.y + k1v.y + bkv.y;
            Ks[j * 68 + c0 + c + 2] = k0v.z + k1v.z + bkv.z;
            Ks[j * 68 + c0 + c + 3] = k0v.w + k1v.w + bkv.w;
            Vt[(c0 + c + 0) * 132 + j] = v0v.x + v1v.x + bvv.x;
            Vt[(c0 + c + 1) * 132 + j] = v0v.y + v1v.y + bvv.y;
            Vt[(c0 + c + 2) * 132 + j] = v0v.z + v1v.z + bvv.z;
            Vt[(c0 + c + 3) * 132 + j] = v0v.w + v1v.w + bvv.w;
        }
    }
    {
        int rid = tid >> 4, c4 = (tid & 15) * 4;
        int grow = b * 128 + tt * 16 + rid;
        const float* q0 = pw + (size_t)grow * 1536 + hh * 64 + c4;
        float4 a = *(const float4*)q0;
        float4 a1 = *(const float4*)(q0 + 786432);
        float4 bb = *(const float4*)(bq + hh * 64 + c4);
        Qs[rid][c4 + 0] = a.x + a1.x + bb.x;
        Qs[rid][c4 + 1] = a.y + a1.y + bb.y;
        Qs[rid][c4 + 2] = a.z + a1.z + bb.z;
        Qs[rid][c4 + 3] = a.w + a1.w + bb.w;
    }
    __syncthreads();
    {
        int j = tid & 127, th = tid >> 7;
        float acc[8] = {0.f, 0.f, 0.f, 0.f, 0.f, 0.f, 0.f, 0.f};
        for (int d0 = 0; d0 < 64; d0 += 4) {
            float4 kv = *(const float4*)&Ks[j * 68 + d0];
#pragma unroll
            for (int r = 0; r < 8; ++r) {
                float4 qv = *(const float4*)&Qs[th * 8 + r][d0];
                acc[r] += qv.x * kv.x + qv.y * kv.y + qv.z * kv.z + qv.w * kv.w;
            }
        }
        const float* tsr = tsym + ((size_t)b << 14) + (size_t)(tt * 16 + th * 8) * 128 + j;
#pragma unroll
        for (int r = 0; r < 8; ++r) {
            int t = th * 8 + r;
            float sv = (tsr[r * 128] > 0.f) ? acc[r] * 0.125f : -INFINITY;
            Ss[t * 132 + j] = sv;
        }
    }
    __syncthreads();
    {
        int row = tid >> 4, l16 = tid & 15;
        float v[8]; float m = -INFINITY;
#pragma unroll
        for (int c = 0; c < 8; ++c) { v[c] = Ss[row * 132 + l16 + c * 16]; m = fmaxf(m, v[c]); }
#pragma unroll
        for (int off = 8; off; off >>= 1) m = fmaxf(m, __shfl_xor(m, off));
        float ssum = 0.f;
#pragma unroll
        for (int c = 0; c < 8; ++c) {
            float e = (v[c] == -INFINITY) ? 0.f : __expf(v[c] - m);
            v[c] = e; ssum += e;
        }
#pragma unroll
        for (int off = 8; off; off >>= 1) ssum += __shfl_xor(ssum, off);
        float inv = 1.0f / (ssum + 1e-12f);
#pragma unroll
        for (int c = 0; c < 8; ++c) Ss[row * 132 + l16 + c * 16] = v[c] * inv;
    }
    __syncthreads();
    {
        int d = tid & 63, tq = tid >> 6;
        float a0 = 0.f, a1 = 0.f, a2 = 0.f, a3 = 0.f;
        for (int j0 = 0; j0 < 128; j0 += 4) {
            float4 vv = *(const float4*)&Vt[d * 132 + j0];
            float4 s0 = *(const float4*)&Ss[(tq * 4 + 0) * 132 + j0];
            float4 s1 = *(const float4*)&Ss[(tq * 4 + 1) * 132 + j0];
            float4 s2 = *(const float4*)&Ss[(tq * 4 + 2) * 132 + j0];
            float4 s3 = *(const float4*)&Ss[(tq * 4 + 3) * 132 + j0];
            a0 += s0.x * vv.x + s0.y * vv.y + s0.z * vv.z + s0.w * vv.w;
            a1 += s1.x * vv.x + s1.y * vv.y + s1.z * vv.z + s1.w * vv.w;
            a2 += s2.x * vv.x + s2.y * vv.y + s2.z * vv.z + s2.w * vv.w;
            a3 += s3.x * vv.x + s3.y * vv.y + s3.z * vv.z + s3.w * vv.w;
        }
        float accv[4] = {a0, a1, a2, a3};
        int growbase = b * 128 + tt * 16;
#pragma unroll
        for (int i = 0; i < 4; ++i) {
            int t = tq * 4 + i;
            agg16[(size_t)(growbase + t) * 512 + hh * 64 + d] = f2h(accv[i]);
        }
    }
}

// ---------------- aebe reduce (inline concat bias) ----------------
__global__ __launch_bounds__(256) void redae_k(const float* __restrict__ part,
                                               const float* __restrict__ eb1,
                                               float* __restrict__ aebe) {
    int idx = blockIdx.x * 256 + threadIdx.x;   // 512*128
    int col = idx & 127;
    float v = col < 64 ? eb1[col] : 0.0f;
#pragma unroll
    for (int z = 0; z < 4; ++z) v += part[(size_t)z * 65536 + idx];
    aebe[idx] = v;
}

// ---------------- dense cross-term GEMM (fp16): C3[b,i,j,o] = ((x[b,i]*x[b,j]) @ W1c)[o] ----------------
__global__ __launch_bounds__(256) void cross_k(const float* __restrict__ x,
                                               const u16* __restrict__ ect,
                                               float* __restrict__ C3) {
    int i = blockIdx.x, b = blockIdx.y;
    __shared__ float xis[512];
    __shared__ u16 As[2][128][32];   // [buf][row j][32 fp16], slot ^= ((row>>1)&3)
    int tid = threadIdx.x;
    {
        const float* xip = x + (size_t)(b * 128 + i) * 512;
        xis[tid] = xip[tid];
        xis[tid + 256] = xip[tid + 256];
    }
    int r = tid >> 1, half = tid & 1, koff = half * 16;
    const float* xr = x + (size_t)(b * 128 + r) * 512 + koff;
    int sw_r = (r >> 1) & 3;
    int lane = tid & 63, w = tid >> 6;
    int m0 = (w & 1) * 64, n0 = (w >> 1) * 32;
    int l15 = lane & 15, lsl = lane >> 4, kf = lsl * 8;
    const u16* pB0 = ect + (size_t)(n0 + l15) * 512 + kf;
    const u16* pB1 = ect + (size_t)(n0 + 16 + l15) * 512 + kf;
    f32x4 acc[4][2] = {};

    auto stageA = [&](int buf, int kbase) {
        float4 v0 = *(const float4*)(xr + kbase);
        float4 v1 = *(const float4*)(xr + kbase + 4);
        float4 v2 = *(const float4*)(xr + kbase + 8);
        float4 v3 = *(const float4*)(xr + kbase + 12);
        float xv[16] = {v0.x, v0.y, v0.z, v0.w, v1.x, v1.y, v1.z, v1.w,
                        v2.x, v2.y, v2.z, v2.w, v3.x, v3.y, v3.z, v3.w};
        short8 h0, h1;
#pragma unroll
        for (int q = 0; q < 8; ++q)
            h0[q] = (short)f2h(xv[q] * xis[kbase + koff + q]);
#pragma unroll
        for (int q = 0; q < 8; ++q)
            h1[q] = (short)f2h(xv[8 + q] * xis[kbase + koff + 8 + q]);
        *(short8*)&As[buf][r][((2 * half + 0) ^ sw_r) * 8] = h0;
        *(short8*)&As[buf][r][((2 * half + 1) ^ sw_r) * 8] = h1;
    };
    auto computeC = [&](int buf, int kbase) {
        f16x8 b0 = *(const f16x8*)(pB0 + kbase);
        f16x8 b1 = *(const f16x8*)(pB1 + kbase);
#pragma unroll
        for (int mf = 0; mf < 4; ++mf) {
            int rA = m0 + mf * 16 + l15;
            f16x8 ah = *(const f16x8*)&As[buf][rA][(lsl ^ ((rA >> 1) & 3)) * 8];
            acc[mf][0] = __builtin_amdgcn_mfma_f32_16x16x32_f16(ah, b0, acc[mf][0], 0, 0, 0);
            acc[mf][1] = __builtin_amdgcn_mfma_f32_16x16x32_f16(ah, b1, acc[mf][1], 0, 0, 0);
        }
    };

    __syncthreads();           // xis ready
    stageA(0, 0);
    __syncthreads();
    for (int s = 0; s < 16; ++s) {
        if (s < 15) stageA((s + 1) & 1, (s + 1) * 32);
        computeC(s & 1, s * 32);
        __syncthreads();
    }

    float* outp = C3 + (size_t)(b * 128 + i) * 128 * 64;
#pragma unroll
    for (int mf = 0; mf < 4; ++mf)
#pragma unroll
        for (int nf = 0; nf < 2; ++nf)
#pragma unroll
            for (int q = 0; q < 4; ++q)
                outp[(size_t)(m0 + mf * 16 + lsl * 4 + q) * 64 + (n0 + nf * 16 + l15)] = acc[mf][nf][q];
}

// ---------------- per-edge finish: gelu(C3+ae+be) -> layer2 -> layer3 -> sigmoid ----------------
__global__ __launch_bounds__(256) void efin_k(const int* __restrict__ ei, int E,
                                              const float* __restrict__ C3,
                                              const float* __restrict__ aebe,
                                              const float* __restrict__ ew2, const float* __restrict__ eb2,
                                              const float* __restrict__ ew3, const float* __restrict__ eb3,
                                              float* __restrict__ P) {
    __shared__ float G1[32][66];
    __shared__ float G2[32][66];
    __shared__ int s_src[32], s_dst[32];
    int tid = threadIdx.x;
    int e0 = blockIdx.x * 32;
    if (tid < 32) {
        int e = e0 + tid;
        s_src[tid] = e < E ? ei[e] : 0;
        s_dst[tid] = e < E ? ei[E + e] : 0;
    }
    __syncthreads();
    {
        int e = tid >> 3, c8 = (tid & 7) * 8;
        int s = s_src[e], d = s_dst[e];
        int bB = s >> 7, i2 = s & 127, j2 = d & 127;
        const float* c3 = C3 + ((size_t)(bB * 128 + i2) * 128 + j2) * 64 + c8;
        const float* ap = aebe + (size_t)s * 128 + c8;
        const float* bp = aebe + (size_t)d * 128 + 64 + c8;
#pragma unroll
        for (int q = 0; q < 8; ++q)
            G1[e][c8 + q] = gelu_f(c3[q] + ap[q] + bp[q]);
    }
    __syncthreads();
    {
        int col = tid & 63, eq = tid >> 6;
        float acc[8];
#pragma unroll
        for (int i = 0; i < 8; ++i) acc[i] = eb2[col];
        for (int m = 0; m < 64; ++m) {
            float wv = ew2[m * 64 + col];
#pragma unroll
            for (int i = 0; i < 8; ++i) acc[i] += G1[eq * 8 + i][m] * wv;
        }
#pragma unroll
        for (int i = 0; i < 8; ++i) G2[eq * 8 + i][col] = gelu_f(acc[i]);
    }
    __syncthreads();
    {
        int el2 = tid >> 3, c8 = (tid & 7) * 8;
        float p = 0.f;
#pragma unroll
        for (int i = 0; i < 8; ++i) p += G2[el2][c8 + i] * ew3[c8 + i];
        p += __shfl_xor(p, 1); p += __shfl_xor(p, 2); p += __shfl_xor(p, 4);
        if ((tid & 7) == 0 && e0 + el2 < E) {
            float logit = p + eb3[0];
            int s = s_src[el2], d2 = s_dst[el2];
            int bB = s >> 7, i2 = s & 127, j2 = d2 & 127;
            P[(bB << 14) + (i2 << 7) + j2] = 1.0f / (1.0f + expf(-logit));
        }
    }
}

// ---------------- final symmetrize + mask ----------------
__global__ __launch_bounds__(256) void final_k(const float* __restrict__ tsym,
                                               const float* __restrict__ P,
                                               float* __restrict__ out) {
    int idx = blockIdx.x * 256 + threadIdx.x;
    int b = idx >> 14, i = (idx >> 7) & 127, j = idx & 127;
    float o = 0.0f;
    if (i != j && tsym[idx] > 0.0f)
        o = 0.5f * (P[idx] + P[(b << 14) + (j << 7) + i]);
    out[idx] = o;
}

extern "C" void kernel_launch(void* const* d_in, const int* in_sizes, int n_in,
                              void* d_out, int out_size, void* d_ws, size_t ws_size,
                              hipStream_t stream) {
    const float* topo   = (const float*)d_in[0];
    const float* weight = (const float*)d_in[1];
    const int*   ei     = (const int*)d_in[2];
    const float* w_topo = (const float*)d_in[3];
    const float* b_topo = (const float*)d_in[4];
    const float* w_w    = (const float*)d_in[5];
    const float* b_w    = (const float*)d_in[6];
    const float* n_emb  = (const float*)d_in[7];
    const float* wq = (const float*)d_in[8];  const float* bq = (const float*)d_in[9];
    const float* wk = (const float*)d_in[10]; const float* bk = (const float*)d_in[11];
    const float* wv = (const float*)d_in[12]; const float* bv = (const float*)d_in[13];
    const float* wo = (const float*)d_in[14]; const float* bo = (const float*)d_in[15];
    const float* w1 = (const float*)d_in[16]; const float* b1 = (const float*)d_in[17];
    const float* w2 = (const float*)d_in[18]; const float* b2 = (const float*)d_in[19];
    const float* ew1 = (const float*)d_in[20]; const float* eb1 = (const float*)d_in[21];
    const float* ew2 = (const float*)d_in[22]; const float* eb2 = (const float*)d_in[23];
    const float* ew3 = (const float*)d_in[24]; const float* eb3 = (const float*)d_in[25];
    const int E = in_sizes[2] / 2;

    char* base = (char*)d_ws;
    size_t off = 0;
    auto alloc = [&](size_t bytes) { char* p = base + off; off += (bytes + 255) & ~(size_t)255; return p; };
    u16* qkvt = (u16*)alloc(3145728 * 2);
    u16* wot  = (u16*)alloc(1048576 * 2);
    u16* w1t  = (u16*)alloc(4194304 * 2);
    u16* w2t  = (u16*)alloc(4194304 * 2);
    u16* eabt = (u16*)alloc(65536 * 2);
    u16* ect  = (u16*)alloc(32768 * 2);
    u16* h16   = (u16*)alloc(262144 * 2);
    u16* agg16 = (u16*)alloc(262144 * 2);
    u16* mid16 = (u16*)alloc(1048576 * 2);
    u16* x16   = (u16*)alloc(262144 * 2);
    float* tsym  = (float*)alloc(65536 * 4);
    float* x     = (float*)alloc(262144 * 4);
    float* aebe  = (float*)alloc(65536 * 4);
    float* P     = (float*)alloc(65536 * 4);
    float* pw    = (float*)alloc(1572864 * 4);           // split-K partials (max: qkv 2x512x1536)
    float* C3    = (float*)alloc((size_t)16777216 * 4);  // dense cross term (B,N,N,64)

    prep_k<<<3096, 256, 0, stream>>>(wq, wk, wv, wo, w1, w2, ew1,
                                     qkvt, wot, w1t, w2t, eabt, ect);
    x0row_k<<<512, 256, 0, stream>>>(topo, weight, w_topo, b_topo, w_w, b_w, n_emb,
                                     tsym, x, h16);

    for (int d = 0; d < 4; ++d) {
        // QKV: split-K x2 -> partials; bias+reduce fused into attn
        gemm2<256, true, false, false, false, false, false><<<dim3(24, 8, 2), 256, 0, stream>>>(
            h16, qkvt + (size_t)d * 1536 * 512,
            nullptr, nullptr, nullptr, nullptr, pw, 512, 1536);
        attn_k<<<dim3(8, 8, 4), 256, 0, stream>>>(pw, bq + d * 512, bk + d * 512, bv + d * 512,
                                                  tsym, agg16);
        // WO: split-K x4 -> partials -> fused reduce+res+LN
        gemm2<128, true, false, false, false, false, false><<<dim3(8, 8, 4), 256, 0, stream>>>(
            agg16, wot + (size_t)d * 512 * 512,
            nullptr, nullptr, nullptr, nullptr, pw, 512, 512);
        redln_k<4, true, false><<<512, 256, 0, stream>>>(pw, bo + d * 512, x, h16);
        // MLP1: full-K, gelu + fp16 out
        gemm2<512, false, true, false, false, true, false><<<dim3(32, 8, 1), 256, 0, stream>>>(
            h16, w1t + (size_t)d * 2048 * 512,
            b1 + d * 2048, nullptr, nullptr, mid16, nullptr, 512, 2048);
        // MLP2: split-K x4 -> partials -> fused reduce+res (+LN | +fp16)
        gemm2<512, true, false, false, false, false, false><<<dim3(8, 8, 4), 256, 0, stream>>>(
            mid16, w2t + (size_t)d * 512 * 2048,
            nullptr, nullptr, nullptr, nullptr, pw, 2048, 512);
        if (d < 3) {
            redln_k<4, true, false><<<512, 256, 0, stream>>>(pw, b2 + d * 512, x, h16);
        } else {
            redln_k<4, false, true><<<512, 256, 0, stream>>>(pw, b2 + d * 512, x, x16);
        }
    }

    // edge-final MLP: aebe via split-K x4 + reduce; dense cross GEMM; per-edge finish
    gemm2<128, true, false, false, false, false, false><<<dim3(2, 8, 4), 256, 0, stream>>>(
        x16, eabt, nullptr, nullptr, nullptr, nullptr, pw, 512, 128);
    redae_k<<<256, 256, 0, stream>>>(pw, eb1, aebe);
    cross_k<<<dim3(128, 4), 256, 0, stream>>>(x, ect, C3);
    efin_k<<<(E + 31) / 32, 256, 0, stream>>>(ei, E, C3, aebe, ew2, eb2, ew3, eb3, P);
    final_k<<<256, 256, 0, stream>>>(tsym, P, (float*)d_out);
}